// Round 4
// baseline (768.120 us; speedup 1.0000x reference)
//
#include <hip/hip_runtime.h>

#define EPS 1e-5f
typedef unsigned short u16;
typedef __attribute__((ext_vector_type(8))) short short8;
typedef __attribute__((ext_vector_type(4))) float f32x4;

__device__ __forceinline__ float bf2f(u16 u) {
  union { unsigned int i; float f; } c; c.i = ((unsigned int)u) << 16; return c.f;
}
__device__ __forceinline__ u16 f2bf(float f) {
  union { float f; unsigned int i; } c; c.f = f;
  unsigned int u = c.i;
  u += 0x7fffu + ((u >> 16) & 1u);   // round-to-nearest-even
  return (u16)(u >> 16);
}
__device__ __forceinline__ float bits2f(unsigned int b) {
  union { unsigned int i; float f; } c; c.i = b; return c.f;
}

// ---------- input BN stats: per j = v*3+c over (n,t) ----------
__global__ __launch_bounds__(256) void k_bn_in_stats(const float* __restrict__ x,
    const float* __restrict__ g, const float* __restrict__ b,
    float* __restrict__ iscale, float* __restrict__ ishift) {
  const int j = blockIdx.x;            // 0..74
  const int c = j % 3, v = j / 3;
  const int tid = threadIdx.x;
  float s = 0.f, q = 0.f;
  for (int i = tid; i < 2400; i += 256) {
    const int n = i / 300, t = i % 300;
    const float val = x[(((size_t)n*3 + c)*300 + t)*25 + v];
    s += val; q += val*val;
  }
  __shared__ float rs[256], rq[256];
  rs[tid] = s; rq[tid] = q;
  __syncthreads();
  for (int off = 128; off > 0; off >>= 1) {
    if (tid < off) { rs[tid] += rs[tid+off]; rq[tid] += rq[tid+off]; }
    __syncthreads();
  }
  if (tid == 0) {
    const float mean = rs[0] / 2400.f;
    const float var  = rq[0] / 2400.f - mean*mean;
    const float sc = g[j] * rsqrtf(var + EPS);
    iscale[j] = sc;
    ishift[j] = b[j] - mean*sc;
  }
}

// ---------- fused input-BN apply + fin (3 -> 64), writes bf16 H_ct ----------
__global__ __launch_bounds__(256) void k_fin(const float* __restrict__ x,
    const float* __restrict__ iscale, const float* __restrict__ ishift,
    const float* __restrict__ fW, const float* __restrict__ fb,
    u16* __restrict__ H) {
  const int n = blockIdx.y;
  const int t0 = blockIdx.x * 10;
  const int tid = threadIdx.x;
  __shared__ float xn[3][250];
  __shared__ float wsh[64][3];
  __shared__ float bsh[64];
  if (tid < 192) wsh[tid/3][tid%3] = fW[tid];
  if (tid < 64)  bsh[tid] = fb[tid];
  for (int i = tid; i < 750; i += 256) {
    const int c = i / 250, pos = i % 250;
    const int t = t0 + pos/25, v = pos%25;
    const int j = v*3 + c;
    xn[c][pos] = x[(((size_t)n*3 + c)*300 + t)*25 + v] * iscale[j] + ishift[j];
  }
  __syncthreads();
  for (int e = tid; e < 64*250; e += 256) {
    const int o = e / 250, pos = e % 250;
    float acc = bsh[o]
              + xn[0][pos]*wsh[o][0] + xn[1][pos]*wsh[o][1] + xn[2][pos]*wsh[o][2];
    const int t = t0 + pos/25, v = pos%25;
    H[(((size_t)n*64 + o)*300 + t)*25 + v] = f2bf(acc);
  }
}

// ---------- prep: A' = A * imp per layer (fp32) ----------
__global__ void k_prep_A(const float* __restrict__ A,
    const float* __restrict__ i0, const float* __restrict__ i1,
    const float* __restrict__ i2, const float* __restrict__ i3,
    float* __restrict__ Ap) {
  const int idx = blockIdx.x*256 + threadIdx.x;
  if (idx >= 7500) return;
  const int layer = idx / 1875, r = idx % 1875;
  const int vw = r % 625;
  const float* imp = (layer==0) ? i0 : (layer==1) ? i1 : (layer==2) ? i2 : i3;
  Ap[idx] = A[r] * imp[vw];
}

// ---------- prep: Wt[co][p*cin+ci] = bf16(W[(p*cout+co)*cin+ci]) ----------
__global__ void k_prep_w(const float* __restrict__ W, u16* __restrict__ Wt,
    int cin, int cout, int P) {
  const int idx = blockIdx.x*256 + threadIdx.x;
  const int K = P*cin;
  if (idx >= cout*K) return;
  const int co = idx / K, k = idx % K;
  const int p = k / cin, ci = k % cin;
  Wt[idx] = f2bf(W[((size_t)(p*cout + co))*cin + ci]);
}

// ---------- xa2: XA[n][t*25+w][p*cin+ci] = sum_v H[ci][t][v] * A'[p][v][w] ----------
// A' read via wave-uniform scalar loads (s_load); x row in packed-u32 regs.
// Processes a pair of timesteps per block (t0 even -> 4B-aligned u32 staging).
// Optionally writes Hmk[n][t*25+v][ci] (K-major H copy) from the p==0 threads.
__global__ __launch_bounds__(256) void k_xa2(const u16* __restrict__ H,
    const float* __restrict__ Ap, u16* __restrict__ XA, u16* Hmk,
    int cin, int log2cin) {
  const int t0 = blockIdx.x * 2;       // 150 t-pairs
  const int n  = blockIdx.y;
  const int tid = threadIdx.x;
  const int K = 3 * cin;
  extern __shared__ unsigned int xs[];  // [cin][27] packed bf16 pairs (50 elems/row)

  // stage: 25 u32 words per ci (covers t0 and t0+1 rows, 50 bf16)
  for (int idx = tid; idx < cin*25; idx += 256) {
    const int ci = idx / 25, c = idx % 25;
    const char* src = (const char*)H + ((((size_t)n*cin + ci)*7500) + (size_t)t0*25)*2 + c*4;
    xs[ci*27 + c] = *(const unsigned int*)src;
  }
  __syncthreads();

  for (int kc = 0; kc < K; kc += 256) {
    const int k = kc + tid;
    if (k < K) {                        // wave-uniform (K multiple of 64)
      const int ci = k & (cin - 1);
      const int p  = __builtin_amdgcn_readfirstlane(k >> log2cin);
      const float* __restrict__ Ab = Ap + p*625;

      unsigned int raw[25];
      #pragma unroll
      for (int j = 0; j < 25; ++j) raw[j] = xs[ci*27 + j];

      #pragma unroll
      for (int tl = 0; tl < 2; ++tl) {
        float acc[25];
        #pragma unroll
        for (int w = 0; w < 25; ++w) acc[w] = 0.f;
        #pragma unroll
        for (int v = 0; v < 25; ++v) {
          const int e = tl*25 + v;
          const unsigned int bits = (e & 1) ? (raw[e>>1] & 0xffff0000u)
                                            : (raw[e>>1] << 16);
          const float xv = bits2f(bits);
          #pragma unroll
          for (int w = 0; w < 25; ++w)
            acc[w] = fmaf(Ab[v*25 + w], xv, acc[w]);   // sgpr * vgpr fmac
        }
        const size_t mbase = ((size_t)n*300 + (t0 + tl))*25;
        #pragma unroll
        for (int w = 0; w < 25; ++w)
          XA[(mbase + w)*K + k] = f2bf(acc[w]);
      }

      if (Hmk && p == 0) {
        #pragma unroll
        for (int tl = 0; tl < 2; ++tl) {
          const size_t mb = ((size_t)n*300 + (t0 + tl))*25;
          #pragma unroll
          for (int v = 0; v < 25; ++v) {
            const int e = tl*25 + v;
            const unsigned int bits = (e & 1) ? (raw[e>>1] >> 16)
                                              : (raw[e>>1] & 0xffffu);
            Hmk[(mb + v)*cin + ci] = (u16)bits;
          }
        }
      }
    }
  }
}

// ---------- bf16 MFMA GEMM ----------
// A: bf16, per n at Asrc + n*7500*K, row m (7500 rows), k contiguous
// B: Wt bf16 [N][K]  (k contiguous)
// C: out[(n*N+co)*7500 + m], fp32 (store_bf16=0) or bf16 (=1)
__global__ __launch_bounds__(256) void k_gemm(const u16* __restrict__ Asrc,
    const u16* __restrict__ Bsrc, float* __restrict__ Cf, u16* __restrict__ Cb,
    int K, int N, int store_bf16) {
  const int m0 = blockIdx.x * 128;
  const int n0 = blockIdx.y * 64;
  const int n  = blockIdx.z;
  const int tid = threadIdx.x;
  const int lane = tid & 63, wid = tid >> 6;
  const int wm = (wid & 1) * 64, wn = (wid >> 1) * 32;

  __shared__ u16 As[128*64];
  __shared__ u16 Bs[64*64];

  const u16* An = Asrc + (size_t)n * 7500 * K;

  f32x4 acc[4][2];
  #pragma unroll
  for (int mi = 0; mi < 4; ++mi)
    #pragma unroll
    for (int ni = 0; ni < 2; ++ni) acc[mi][ni] = (f32x4){0.f,0.f,0.f,0.f};

  const int nkt = K >> 6;
  for (int kt = 0; kt < nkt; ++kt) {
    const int kbase = kt * 64;
    __syncthreads();
    #pragma unroll
    for (int i = 0; i < 4; ++i) {
      const int idx = tid + i*256;
      const int r = idx >> 3, c = idx & 7;
      int m = m0 + r; if (m > 7499) m = 7499;
      const short8 val = *(const short8*)(An + (size_t)m*K + kbase + c*8);
      *(short8*)&As[r*64 + ((c ^ (r & 7)) * 8)] = val;
    }
    #pragma unroll
    for (int i = 0; i < 2; ++i) {
      const int idx = tid + i*256;
      const int r = idx >> 3, c = idx & 7;
      const short8 val = *(const short8*)(Bsrc + (size_t)(n0 + r)*K + kbase + c*8);
      *(short8*)&Bs[r*64 + ((c ^ (r & 7)) * 8)] = val;
    }
    __syncthreads();
    #pragma unroll
    for (int kc = 0; kc < 2; ++kc) {
      const int kchunk = kc*4 + (lane >> 4);
      short8 a[4], b[2];
      #pragma unroll
      for (int mi = 0; mi < 4; ++mi) {
        const int m = wm + mi*16 + (lane & 15);
        a[mi] = *(const short8*)&As[m*64 + ((kchunk ^ (m & 7)) * 8)];
      }
      #pragma unroll
      for (int ni = 0; ni < 2; ++ni) {
        const int r = wn + ni*16 + (lane & 15);
        b[ni] = *(const short8*)&Bs[r*64 + ((kchunk ^ (r & 7)) * 8)];
      }
      #pragma unroll
      for (int mi = 0; mi < 4; ++mi)
        #pragma unroll
        for (int ni = 0; ni < 2; ++ni)
          acc[mi][ni] = __builtin_amdgcn_mfma_f32_16x16x32_bf16(a[mi], b[ni], acc[mi][ni], 0, 0, 0);
    }
  }

  const int mrow = (lane >> 4) * 4;
  #pragma unroll
  for (int mi = 0; mi < 4; ++mi) {
    const int mb = m0 + wm + mi*16 + mrow;
    if (mb >= 7500) continue;
    #pragma unroll
    for (int ni = 0; ni < 2; ++ni) {
      const int co = n0 + wn + ni*16 + (lane & 15);
      const size_t off = ((size_t)n * N + co) * 7500 + mb;
      if (store_bf16) {
        unsigned long long pk =
            (unsigned long long)f2bf(acc[mi][ni][0]) |
            ((unsigned long long)f2bf(acc[mi][ni][1]) << 16) |
            ((unsigned long long)f2bf(acc[mi][ni][2]) << 32) |
            ((unsigned long long)f2bf(acc[mi][ni][3]) << 48);
        *(unsigned long long*)&Cb[off] = pk;
      } else {
        *(f32x4*)&Cf[off] = acc[mi][ni];
      }
    }
  }
}

// ---------- BN partial stats of windowed sum S (from fp32 Z), per (c,n) ----------
__global__ __launch_bounds__(256) void k_bn_part_win(const float* __restrict__ G,
    float* __restrict__ part, int cout) {
  const int c = blockIdx.x, n = blockIdx.y;
  const int tid = threadIdx.x;
  const float* gb = G + ((size_t)n*cout + c)*7500;
  float s = 0.f, q = 0.f;
  for (int i = tid; i < 7500; i += 256) {
    const int ss = i / 25, w = i % 25;
    float S = 0.f;
    if (ss >= 8) {
      #pragma unroll
      for (int d = 0; d < 9; ++d) S += gb[i - d*25];
    } else {
      for (int tt = 0; tt <= ss; ++tt) S += gb[tt*25 + w];
    }
    s += S; q += S*S;
  }
  __shared__ float rs[256], rq[256];
  rs[tid] = s; rq[tid] = q;
  __syncthreads();
  for (int off = 128; off > 0; off >>= 1) {
    if (tid < off) { rs[tid] += rs[tid+off]; rq[tid] += rq[tid+off]; }
    __syncthreads();
  }
  if (tid == 0) {
    part[((size_t)c*8 + n)*2]     = rs[0];
    part[((size_t)c*8 + n)*2 + 1] = rq[0];
  }
}

// ---------- BN partial stats, plain (bf16 residual R) ----------
__global__ __launch_bounds__(256) void k_bn_part_plain(const u16* __restrict__ R,
    float* __restrict__ part, int cout) {
  const int c = blockIdx.x, n = blockIdx.y;
  const int tid = threadIdx.x;
  const u16* rb = R + ((size_t)n*cout + c)*7500;
  float s = 0.f, q = 0.f;
  for (int i = tid; i < 7500; i += 256) {
    const float val = bf2f(rb[i]);
    s += val; q += val*val;
  }
  __shared__ float rs[256], rq[256];
  rs[tid] = s; rq[tid] = q;
  __syncthreads();
  for (int off = 128; off > 0; off >>= 1) {
    if (tid < off) { rs[tid] += rs[tid+off]; rq[tid] += rq[tid+off]; }
    __syncthreads();
  }
  if (tid == 0) {
    part[((size_t)c*8 + n)*2]     = rs[0];
    part[((size_t)c*8 + n)*2 + 1] = rq[0];
  }
}

// ---------- finalize BN ----------
__global__ void k_bn_finalize(const float* __restrict__ part,
    const float* __restrict__ g, const float* __restrict__ b,
    float* __restrict__ scale, float* __restrict__ shift, int cout) {
  const int c = blockIdx.x * 64 + threadIdx.x;
  if (c >= cout) return;
  float s = 0.f, q = 0.f;
  for (int n = 0; n < 8; ++n) {
    s += part[((size_t)c*8 + n)*2];
    q += part[((size_t)c*8 + n)*2 + 1];
  }
  const float mean = s / 60000.f;
  const float var  = q / 60000.f - mean*mean;
  const float sc = g[c] * rsqrtf(var + EPS);
  scale[c] = sc;
  shift[c] = b[c] - mean*sc;
}

// ---------- fused window-sum + BN + relu + residual; writes bf16 H ----------
__global__ __launch_bounds__(256) void k_apply(const float* __restrict__ G,
    const u16* __restrict__ Rb, const u16* Hres,
    const float* __restrict__ scale, const float* __restrict__ shift,
    const float* __restrict__ rscale, const float* __restrict__ rshift,
    u16* Out, int cout, int mode) {
  const int bc = blockIdx.x;          // n*cout + c
  const int c = bc % cout;
  const float* gb = G + (size_t)bc * 7500;
  const float sc = scale[c], sh = shift[c];
  float rsc = 0.f, rsh = 0.f;
  if (mode == 1) { rsc = rscale[c]; rsh = rshift[c]; }
  for (int i = threadIdx.x; i < 7500; i += 256) {
    const int ss = i / 25, w = i % 25;
    float S = 0.f;
    if (ss >= 8) {
      #pragma unroll
      for (int d = 0; d < 9; ++d) S += gb[i - d*25];
    } else {
      for (int tt = 0; tt <= ss; ++tt) S += gb[tt*25 + w];
    }
    const float h = fmaxf(S*sc + sh, 0.f);
    float o;
    if (mode == 0)      o = h;
    else if (mode == 1) o = fmaxf(h + (bf2f(Rb[(size_t)bc*7500 + i])*rsc + rsh), 0.f);
    else                o = fmaxf(h + bf2f(Hres[(size_t)bc*7500 + i]), 0.f);
    Out[(size_t)bc*7500 + i] = f2bf(o);
  }
}

// ---------- mean pool over joints (bf16 in, fp32 out) ----------
__global__ void k_pool(const u16* __restrict__ H, float* __restrict__ HP) {
  const int idx = blockIdx.x*256 + threadIdx.x;
  if (idx >= 8*256*300) return;
  const u16* base = H + (size_t)idx * 25;
  float s = 0.f;
  #pragma unroll
  for (int v = 0; v < 25; ++v) s += bf2f(base[v]);
  HP[idx] = s * (1.f/25.f);
}

// ---------- classifier conv ----------
__global__ __launch_bounds__(256) void k_fout(const float* __restrict__ HP,
    const float* __restrict__ fW, const float* __restrict__ fb,
    float* __restrict__ out) {
  const int n = blockIdx.y;
  const int t0 = blockIdx.x * 32;
  const int tid = threadIdx.x;
  __shared__ float hp[256][32];
  for (int i = tid; i < 256*32; i += 256) {
    const int c = i / 32, tt = i % 32;
    const int t = t0 + tt;
    hp[c][tt] = (t < 300) ? HP[((size_t)n*256 + c)*300 + t] : 0.f;
  }
  __syncthreads();
  for (int e = tid; e < 60*32; e += 256) {
    const int o = e / 32, tt = e % 32;
    const int t = t0 + tt;
    if (t >= 300) continue;
    float acc = fb[o];
    for (int c = 0; c < 256; ++c) acc += hp[c][tt] * fW[o*256 + c];
    out[((size_t)n*60 + o)*300 + t] = acc;
  }
}

extern "C" void kernel_launch(void* const* d_in, const int* in_sizes, int n_in,
                              void* d_out, int out_size, void* d_ws, size_t ws_size,
                              hipStream_t stream) {
  (void)in_sizes; (void)n_in; (void)out_size; (void)ws_size;
  const float* x     = (const float*)d_in[0];
  const float* A     = (const float*)d_in[1];
  const float* bng   = (const float*)d_in[2];
  const float* bnb   = (const float*)d_in[3];
  const float* finW  = (const float*)d_in[4];
  const float* finb  = (const float*)d_in[5];
  const float* imp0  = (const float*)d_in[6];
  const float* imp1  = (const float*)d_in[7];
  const float* imp2  = (const float*)d_in[8];
  const float* imp3  = (const float*)d_in[9];
  const float* W0    = (const float*)d_in[10];
  const float* g0    = (const float*)d_in[11];
  const float* b0    = (const float*)d_in[12];
  const float* W1    = (const float*)d_in[13];
  const float* g1    = (const float*)d_in[14];
  const float* b1    = (const float*)d_in[15];
  const float* Wr1   = (const float*)d_in[16];
  const float* gr1   = (const float*)d_in[17];
  const float* br1   = (const float*)d_in[18];
  const float* W2    = (const float*)d_in[19];
  const float* g2    = (const float*)d_in[20];
  const float* b2    = (const float*)d_in[21];
  const float* Wr2   = (const float*)d_in[22];
  const float* gr2   = (const float*)d_in[23];
  const float* br2   = (const float*)d_in[24];
  const float* W3    = (const float*)d_in[25];
  const float* g3    = (const float*)d_in[26];
  const float* b3    = (const float*)d_in[27];
  const float* foutW = (const float*)d_in[28];
  const float* foutb = (const float*)d_in[29];
  float* out = (float*)d_out;

  char* base = (char*)d_ws;
  float* Z    = (float*)base;                      // 15,360,000 f32 (61.44 MB)
  u16*   Hmk  = (u16*)base;                        // overlay in Z region
  u16*   BIGU = (u16*)(base + 61440000);           // 46,080,000 u16 (92.16 MB)
  u16*   XA   = BIGU;
  u16*   Rb   = BIGU + 23040000;
  u16*   Hct  = (u16*)(base + 153600000);          // 15,360,000 u16 (30.72 MB)
  float* HP   = (float*)(base + 184320000);        // 614,400 f32
  u16*   WT   = (u16*)(base + 186777600);          // 372,736 u16
  float* Ap   = (float*)(base + 187523072);        // 7,500 f32
  float* ST   = Ap + 7500;
  float* ISC = ST,         *ISH = ST + 80;
  float* BSC = ST + 160,   *BSH = ST + 416;
  float* RSC = ST + 672,   *RSH = ST + 928;
  float* PART = ST + 1200;                         // 4096

  u16* W0t  = WT;            // 64 x 192
  u16* W1t  = WT + 12288;    // 128 x 192
  u16* Wr1t = WT + 36864;    // 128 x 64
  u16* W2t  = WT + 45056;    // 256 x 384
  u16* Wr2t = WT + 143360;   // 256 x 128
  u16* W3t  = WT + 176128;   // 256 x 768

  // ---- prep ----
  k_prep_A<<<30, 256, 0, stream>>>(A, imp0, imp1, imp2, imp3, Ap);
  k_prep_w<<<48,  256, 0, stream>>>(W0,  W0t,  64,  64,  3);
  k_prep_w<<<96,  256, 0, stream>>>(W1,  W1t,  64,  128, 3);
  k_prep_w<<<32,  256, 0, stream>>>(Wr1, Wr1t, 64,  128, 1);
  k_prep_w<<<384, 256, 0, stream>>>(W2,  W2t,  128, 256, 3);
  k_prep_w<<<128, 256, 0, stream>>>(Wr2, Wr2t, 128, 256, 1);
  k_prep_w<<<768, 256, 0, stream>>>(W3,  W3t,  256, 256, 3);

  k_bn_in_stats<<<75, 256, 0, stream>>>(x, bng, bnb, ISC, ISH);
  k_fin<<<dim3(30, 8), 256, 0, stream>>>(x, ISC, ISH, finW, finb, Hct);

  // ---- layer 0: 64 -> 64 ----
  k_xa2<<<dim3(150, 8), 256, 64*27*4, stream>>>(Hct, Ap, XA, nullptr, 64, 6);
  k_gemm<<<dim3(59, 1, 8), 256, 0, stream>>>(XA, W0t, Z, nullptr, 192, 64, 0);
  k_bn_part_win<<<dim3(64, 8), 256, 0, stream>>>(Z, PART, 64);
  k_bn_finalize<<<1, 64, 0, stream>>>(PART, g0, b0, BSC, BSH, 64);
  k_apply<<<8*64, 256, 0, stream>>>(Z, nullptr, nullptr, BSC, BSH, nullptr, nullptr, Hct, 64, 0);

  // ---- layer 1: 64 -> 128 ----
  k_xa2<<<dim3(150, 8), 256, 64*27*4, stream>>>(Hct, Ap + 1875, XA, Hmk, 64, 6);
  k_gemm<<<dim3(59, 2, 8), 256, 0, stream>>>(Hmk, Wr1t, nullptr, Rb, 64, 128, 1);
  k_bn_part_plain<<<dim3(128, 8), 256, 0, stream>>>(Rb, PART, 128);
  k_bn_finalize<<<2, 64, 0, stream>>>(PART, gr1, br1, RSC, RSH, 128);
  k_gemm<<<dim3(59, 2, 8), 256, 0, stream>>>(XA, W1t, Z, nullptr, 192, 128, 0);
  k_bn_part_win<<<dim3(128, 8), 256, 0, stream>>>(Z, PART, 128);
  k_bn_finalize<<<2, 64, 0, stream>>>(PART, g1, b1, BSC, BSH, 128);
  k_apply<<<8*128, 256, 0, stream>>>(Z, Rb, nullptr, BSC, BSH, RSC, RSH, Hct, 128, 1);

  // ---- layer 2: 128 -> 256 ----
  k_xa2<<<dim3(150, 8), 256, 128*27*4, stream>>>(Hct, Ap + 3750, XA, Hmk, 128, 7);
  k_gemm<<<dim3(59, 4, 8), 256, 0, stream>>>(Hmk, Wr2t, nullptr, Rb, 128, 256, 1);
  k_bn_part_plain<<<dim3(256, 8), 256, 0, stream>>>(Rb, PART, 256);
  k_bn_finalize<<<4, 64, 0, stream>>>(PART, gr2, br2, RSC, RSH, 256);
  k_gemm<<<dim3(59, 4, 8), 256, 0, stream>>>(XA, W2t, Z, nullptr, 384, 256, 0);
  k_bn_part_win<<<dim3(256, 8), 256, 0, stream>>>(Z, PART, 256);
  k_bn_finalize<<<4, 64, 0, stream>>>(PART, g2, b2, BSC, BSH, 256);
  k_apply<<<8*256, 256, 0, stream>>>(Z, Rb, nullptr, BSC, BSH, RSC, RSH, Hct, 256, 1);

  // ---- layer 3: 256 -> 256, identity residual ----
  k_xa2<<<dim3(150, 8), 256, 256*27*4, stream>>>(Hct, Ap + 5625, XA, nullptr, 256, 8);
  k_gemm<<<dim3(59, 4, 8), 256, 0, stream>>>(XA, W3t, Z, nullptr, 768, 256, 0);
  k_bn_part_win<<<dim3(256, 8), 256, 0, stream>>>(Z, PART, 256);
  k_bn_finalize<<<4, 64, 0, stream>>>(PART, g3, b3, BSC, BSH, 256);
  k_apply<<<8*256, 256, 0, stream>>>(Z, nullptr, Hct, BSC, BSH, nullptr, nullptr, Hct, 256, 2);

  // ---- head ----
  k_pool<<<2400, 256, 0, stream>>>(Hct, HP);
  k_fout<<<dim3(10, 8), 256, 0, stream>>>(HP, foutW, foutb, out);
}

// Round 5
// 579.513 us; speedup vs baseline: 1.3255x; 1.3255x over previous
//
#include <hip/hip_runtime.h>

#define EPS 1e-5f
typedef unsigned short u16;
typedef __attribute__((ext_vector_type(8))) short short8;
typedef __attribute__((ext_vector_type(4))) float f32x4;

__device__ __forceinline__ float bf2f(u16 u) {
  union { unsigned int i; float f; } c; c.i = ((unsigned int)u) << 16; return c.f;
}
__device__ __forceinline__ u16 f2bf(float f) {
  union { float f; unsigned int i; } c; c.f = f;
  unsigned int u = c.i;
  u += 0x7fffu + ((u >> 16) & 1u);   // round-to-nearest-even
  return (u16)(u >> 16);
}
__device__ __forceinline__ float bits2f(unsigned int b) {
  union { unsigned int i; float f; } c; c.i = b; return c.f;
}

// ---------- input BN stats: per j = v*3+c over (n,t) ----------
__global__ __launch_bounds__(256) void k_bn_in_stats(const float* __restrict__ x,
    const float* __restrict__ g, const float* __restrict__ b,
    float* __restrict__ iscale, float* __restrict__ ishift) {
  const int j = blockIdx.x;            // 0..74
  const int c = j % 3, v = j / 3;
  const int tid = threadIdx.x;
  float s = 0.f, q = 0.f;
  for (int i = tid; i < 2400; i += 256) {
    const int n = i / 300, t = i % 300;
    const float val = x[(((size_t)n*3 + c)*300 + t)*25 + v];
    s += val; q += val*val;
  }
  __shared__ float rs[256], rq[256];
  rs[tid] = s; rq[tid] = q;
  __syncthreads();
  for (int off = 128; off > 0; off >>= 1) {
    if (tid < off) { rs[tid] += rs[tid+off]; rq[tid] += rq[tid+off]; }
    __syncthreads();
  }
  if (tid == 0) {
    const float mean = rs[0] / 2400.f;
    const float var  = rq[0] / 2400.f - mean*mean;
    const float sc = g[j] * rsqrtf(var + EPS);
    iscale[j] = sc;
    ishift[j] = b[j] - mean*sc;
  }
}

// ---------- fused input-BN apply + fin (3 -> 64), writes bf16 H_ct ----------
__global__ __launch_bounds__(256) void k_fin(const float* __restrict__ x,
    const float* __restrict__ iscale, const float* __restrict__ ishift,
    const float* __restrict__ fW, const float* __restrict__ fb,
    u16* __restrict__ H) {
  const int n = blockIdx.y;
  const int t0 = blockIdx.x * 10;
  const int tid = threadIdx.x;
  __shared__ float xn[3][250];
  __shared__ float wsh[64][3];
  __shared__ float bsh[64];
  if (tid < 192) wsh[tid/3][tid%3] = fW[tid];
  if (tid < 64)  bsh[tid] = fb[tid];
  for (int i = tid; i < 750; i += 256) {
    const int c = i / 250, pos = i % 250;
    const int t = t0 + pos/25, v = pos%25;
    const int j = v*3 + c;
    xn[c][pos] = x[(((size_t)n*3 + c)*300 + t)*25 + v] * iscale[j] + ishift[j];
  }
  __syncthreads();
  for (int e = tid; e < 64*250; e += 256) {
    const int o = e / 250, pos = e % 250;
    float acc = bsh[o]
              + xn[0][pos]*wsh[o][0] + xn[1][pos]*wsh[o][1] + xn[2][pos]*wsh[o][2];
    const int t = t0 + pos/25, v = pos%25;
    H[(((size_t)n*64 + o)*300 + t)*25 + v] = f2bf(acc);
  }
}

// ---------- prep: A' = A * imp per layer (fp32) ----------
__global__ void k_prep_A(const float* __restrict__ A,
    const float* __restrict__ i0, const float* __restrict__ i1,
    const float* __restrict__ i2, const float* __restrict__ i3,
    float* __restrict__ Ap) {
  const int idx = blockIdx.x*256 + threadIdx.x;
  if (idx >= 7500) return;
  const int layer = idx / 1875, r = idx % 1875;
  const int vw = r % 625;
  const float* imp = (layer==0) ? i0 : (layer==1) ? i1 : (layer==2) ? i2 : i3;
  Ap[idx] = A[r] * imp[vw];
}

// ---------- prep: Wt[co][p*cin+ci] = bf16(W[(p*cout+co)*cin+ci]) ----------
__global__ void k_prep_w(const float* __restrict__ W, u16* __restrict__ Wt,
    int cin, int cout, int P) {
  const int idx = blockIdx.x*256 + threadIdx.x;
  const int K = P*cin;
  if (idx >= cout*K) return;
  const int co = idx / K, k = idx % K;
  const int p = k / cin, ci = k % cin;
  Wt[idx] = f2bf(W[((size_t)(p*cout + co))*cin + ci]);
}

// ---------- xa3: XA[n][t*25+w][p*cin+ci] = sum_v H[ci][t][v] * A'[p][v][w] ----------
// A' staged in LDS, read via wave-uniform ds_read_b128 broadcasts (p uniform per wave).
// x row (2 timesteps, 50 bf16 packed in 25 u32) held in registers, statically indexed.
// Each A read feeds 8 FMAs (4 w x 2 t). Optionally emits Hmk (K-major H) from p==0 threads.
__global__ __launch_bounds__(256) void k_xa3(const u16* __restrict__ H,
    const float* __restrict__ Ap, u16* __restrict__ XA, u16* Hmk,
    int cin, int log2cin) {
  const int t0 = blockIdx.x * 2;       // 150 t-pairs
  const int n  = blockIdx.y;
  const int tid = threadIdx.x;
  const int K = 3 * cin;
  extern __shared__ unsigned int xs[]; // [cin][27] packed x ; then A' [3][25][28] floats
  float* As = (float*)(xs + cin*27);

  // stage A' (1875 floats -> padded [p][v][28], 16B-aligned rows)
  for (int i = tid; i < 1875; i += 256) {
    const int p = i / 625, r = i % 625;
    As[p*700 + (r/25)*28 + (r%25)] = Ap[i];
  }
  // stage x: 25 u32 words per ci (covers t0,t0+1 rows = 50 bf16)
  for (int idx = tid; idx < cin*25; idx += 256) {
    const int ci = idx / 25, c = idx % 25;
    const char* src = (const char*)H + ((((size_t)n*cin + ci)*7500) + (size_t)t0*25)*2 + c*4;
    xs[ci*27 + c] = *(const unsigned int*)src;
  }
  __syncthreads();

  for (int kc = 0; kc < K; kc += 256) {
    const int k = kc + tid;
    if (k < K) {                       // K multiple of 64 -> wave-uniform predicate
      const int ci = k & (cin - 1);
      const int p  = k >> log2cin;     // wave-uniform
      const float* __restrict__ Ab = &As[p*700];

      unsigned int raw[25];
      #pragma unroll
      for (int j = 0; j < 25; ++j) raw[j] = xs[ci*27 + j];

      float acc0[25], acc1[25];
      #pragma unroll
      for (int w = 0; w < 25; ++w) { acc0[w] = 0.f; acc1[w] = 0.f; }

      #pragma unroll
      for (int v = 0; v < 25; ++v) {
        const int e1 = 25 + v;
        const float xv0 = bits2f((v & 1)  ? (raw[v  >> 1] & 0xffff0000u)
                                          : (raw[v  >> 1] << 16));
        const float xv1 = bits2f((e1 & 1) ? (raw[e1 >> 1] & 0xffff0000u)
                                          : (raw[e1 >> 1] << 16));
        #pragma unroll
        for (int j = 0; j < 7; ++j) {
          const f32x4 a = *(const f32x4*)&Ab[v*28 + j*4];  // uniform addr -> broadcast
          #pragma unroll
          for (int e = 0; e < 4; ++e) {
            const int w = j*4 + e;
            if (w < 25) {
              acc0[w] = fmaf(a[e], xv0, acc0[w]);
              acc1[w] = fmaf(a[e], xv1, acc1[w]);
            }
          }
        }
      }

      const size_t mb0 = ((size_t)n*300 + t0)*25;
      #pragma unroll
      for (int w = 0; w < 25; ++w) XA[(mb0 + w)*K + k]      = f2bf(acc0[w]);
      #pragma unroll
      for (int w = 0; w < 25; ++w) XA[(mb0 + 25 + w)*K + k] = f2bf(acc1[w]);

      if (Hmk && p == 0) {
        #pragma unroll
        for (int v = 0; v < 25; ++v) {
          const unsigned int b0 = (v & 1) ? (raw[v >> 1] >> 16) : (raw[v >> 1] & 0xffffu);
          Hmk[(mb0 + v)*cin + ci] = (u16)b0;
        }
        #pragma unroll
        for (int v = 0; v < 25; ++v) {
          const int e = 25 + v;
          const unsigned int b1 = (e & 1) ? (raw[e >> 1] >> 16) : (raw[e >> 1] & 0xffffu);
          Hmk[(mb0 + 25 + v)*cin + ci] = (u16)b1;
        }
      }
    }
  }
}

// ---------- bf16 MFMA GEMM ----------
// A: bf16, per n at Asrc + n*7500*K, row m (7500 rows), k contiguous
// B: Wt bf16 [N][K]  (k contiguous)
// C: out[(n*N+co)*7500 + m], fp32 (store_bf16=0) or bf16 (=1)
__global__ __launch_bounds__(256) void k_gemm(const u16* __restrict__ Asrc,
    const u16* __restrict__ Bsrc, float* __restrict__ Cf, u16* __restrict__ Cb,
    int K, int N, int store_bf16) {
  const int m0 = blockIdx.x * 128;
  const int n0 = blockIdx.y * 64;
  const int n  = blockIdx.z;
  const int tid = threadIdx.x;
  const int lane = tid & 63, wid = tid >> 6;
  const int wm = (wid & 1) * 64, wn = (wid >> 1) * 32;

  __shared__ u16 As[128*64];
  __shared__ u16 Bs[64*64];

  const u16* An = Asrc + (size_t)n * 7500 * K;

  f32x4 acc[4][2];
  #pragma unroll
  for (int mi = 0; mi < 4; ++mi)
    #pragma unroll
    for (int ni = 0; ni < 2; ++ni) acc[mi][ni] = (f32x4){0.f,0.f,0.f,0.f};

  const int nkt = K >> 6;
  for (int kt = 0; kt < nkt; ++kt) {
    const int kbase = kt * 64;
    __syncthreads();
    #pragma unroll
    for (int i = 0; i < 4; ++i) {
      const int idx = tid + i*256;
      const int r = idx >> 3, c = idx & 7;
      int m = m0 + r; if (m > 7499) m = 7499;
      const short8 val = *(const short8*)(An + (size_t)m*K + kbase + c*8);
      *(short8*)&As[r*64 + ((c ^ (r & 7)) * 8)] = val;
    }
    #pragma unroll
    for (int i = 0; i < 2; ++i) {
      const int idx = tid + i*256;
      const int r = idx >> 3, c = idx & 7;
      const short8 val = *(const short8*)(Bsrc + (size_t)(n0 + r)*K + kbase + c*8);
      *(short8*)&Bs[r*64 + ((c ^ (r & 7)) * 8)] = val;
    }
    __syncthreads();
    #pragma unroll
    for (int kc = 0; kc < 2; ++kc) {
      const int kchunk = kc*4 + (lane >> 4);
      short8 a[4], b[2];
      #pragma unroll
      for (int mi = 0; mi < 4; ++mi) {
        const int m = wm + mi*16 + (lane & 15);
        a[mi] = *(const short8*)&As[m*64 + ((kchunk ^ (m & 7)) * 8)];
      }
      #pragma unroll
      for (int ni = 0; ni < 2; ++ni) {
        const int r = wn + ni*16 + (lane & 15);
        b[ni] = *(const short8*)&Bs[r*64 + ((kchunk ^ (r & 7)) * 8)];
      }
      #pragma unroll
      for (int mi = 0; mi < 4; ++mi)
        #pragma unroll
        for (int ni = 0; ni < 2; ++ni)
          acc[mi][ni] = __builtin_amdgcn_mfma_f32_16x16x32_bf16(a[mi], b[ni], acc[mi][ni], 0, 0, 0);
    }
  }

  const int mrow = (lane >> 4) * 4;
  #pragma unroll
  for (int mi = 0; mi < 4; ++mi) {
    const int mb = m0 + wm + mi*16 + mrow;
    if (mb >= 7500) continue;
    #pragma unroll
    for (int ni = 0; ni < 2; ++ni) {
      const int co = n0 + wn + ni*16 + (lane & 15);
      const size_t off = ((size_t)n * N + co) * 7500 + mb;
      if (store_bf16) {
        unsigned long long pk =
            (unsigned long long)f2bf(acc[mi][ni][0]) |
            ((unsigned long long)f2bf(acc[mi][ni][1]) << 16) |
            ((unsigned long long)f2bf(acc[mi][ni][2]) << 32) |
            ((unsigned long long)f2bf(acc[mi][ni][3]) << 48);
        *(unsigned long long*)&Cb[off] = pk;
      } else {
        *(f32x4*)&Cf[off] = acc[mi][ni];
      }
    }
  }
}

// ---------- BN partial stats of windowed sum S (from fp32 Z), per (c,n) ----------
__global__ __launch_bounds__(256) void k_bn_part_win(const float* __restrict__ G,
    float* __restrict__ part, int cout) {
  const int c = blockIdx.x, n = blockIdx.y;
  const int tid = threadIdx.x;
  const float* gb = G + ((size_t)n*cout + c)*7500;
  float s = 0.f, q = 0.f;
  for (int i = tid; i < 7500; i += 256) {
    const int ss = i / 25, w = i % 25;
    float S = 0.f;
    if (ss >= 8) {
      #pragma unroll
      for (int d = 0; d < 9; ++d) S += gb[i - d*25];
    } else {
      for (int tt = 0; tt <= ss; ++tt) S += gb[tt*25 + w];
    }
    s += S; q += S*S;
  }
  __shared__ float rs[256], rq[256];
  rs[tid] = s; rq[tid] = q;
  __syncthreads();
  for (int off = 128; off > 0; off >>= 1) {
    if (tid < off) { rs[tid] += rs[tid+off]; rq[tid] += rq[tid+off]; }
    __syncthreads();
  }
  if (tid == 0) {
    part[((size_t)c*8 + n)*2]     = rs[0];
    part[((size_t)c*8 + n)*2 + 1] = rq[0];
  }
}

// ---------- BN partial stats, plain (bf16 residual R) ----------
__global__ __launch_bounds__(256) void k_bn_part_plain(const u16* __restrict__ R,
    float* __restrict__ part, int cout) {
  const int c = blockIdx.x, n = blockIdx.y;
  const int tid = threadIdx.x;
  const u16* rb = R + ((size_t)n*cout + c)*7500;
  float s = 0.f, q = 0.f;
  for (int i = tid; i < 7500; i += 256) {
    const float val = bf2f(rb[i]);
    s += val; q += val*val;
  }
  __shared__ float rs[256], rq[256];
  rs[tid] = s; rq[tid] = q;
  __syncthreads();
  for (int off = 128; off > 0; off >>= 1) {
    if (tid < off) { rs[tid] += rs[tid+off]; rq[tid] += rq[tid+off]; }
    __syncthreads();
  }
  if (tid == 0) {
    part[((size_t)c*8 + n)*2]     = rs[0];
    part[((size_t)c*8 + n)*2 + 1] = rq[0];
  }
}

// ---------- finalize BN ----------
__global__ void k_bn_finalize(const float* __restrict__ part,
    const float* __restrict__ g, const float* __restrict__ b,
    float* __restrict__ scale, float* __restrict__ shift, int cout) {
  const int c = blockIdx.x * 64 + threadIdx.x;
  if (c >= cout) return;
  float s = 0.f, q = 0.f;
  for (int n = 0; n < 8; ++n) {
    s += part[((size_t)c*8 + n)*2];
    q += part[((size_t)c*8 + n)*2 + 1];
  }
  const float mean = s / 60000.f;
  const float var  = q / 60000.f - mean*mean;
  const float sc = g[c] * rsqrtf(var + EPS);
  scale[c] = sc;
  shift[c] = b[c] - mean*sc;
}

// ---------- fused window-sum + BN + relu + residual; writes bf16 H ----------
__global__ __launch_bounds__(256) void k_apply(const float* __restrict__ G,
    const u16* __restrict__ Rb, const u16* Hres,
    const float* __restrict__ scale, const float* __restrict__ shift,
    const float* __restrict__ rscale, const float* __restrict__ rshift,
    u16* Out, int cout, int mode) {
  const int bc = blockIdx.x;          // n*cout + c
  const int c = bc % cout;
  const float* gb = G + (size_t)bc * 7500;
  const float sc = scale[c], sh = shift[c];
  float rsc = 0.f, rsh = 0.f;
  if (mode == 1) { rsc = rscale[c]; rsh = rshift[c]; }
  for (int i = threadIdx.x; i < 7500; i += 256) {
    const int ss = i / 25, w = i % 25;
    float S = 0.f;
    if (ss >= 8) {
      #pragma unroll
      for (int d = 0; d < 9; ++d) S += gb[i - d*25];
    } else {
      for (int tt = 0; tt <= ss; ++tt) S += gb[tt*25 + w];
    }
    const float h = fmaxf(S*sc + sh, 0.f);
    float o;
    if (mode == 0)      o = h;
    else if (mode == 1) o = fmaxf(h + (bf2f(Rb[(size_t)bc*7500 + i])*rsc + rsh), 0.f);
    else                o = fmaxf(h + bf2f(Hres[(size_t)bc*7500 + i]), 0.f);
    Out[(size_t)bc*7500 + i] = f2bf(o);
  }
}

// ---------- mean pool over joints (bf16 in, fp32 out) ----------
__global__ void k_pool(const u16* __restrict__ H, float* __restrict__ HP) {
  const int idx = blockIdx.x*256 + threadIdx.x;
  if (idx >= 8*256*300) return;
  const u16* base = H + (size_t)idx * 25;
  float s = 0.f;
  #pragma unroll
  for (int v = 0; v < 25; ++v) s += bf2f(base[v]);
  HP[idx] = s * (1.f/25.f);
}

// ---------- classifier conv ----------
__global__ __launch_bounds__(256) void k_fout(const float* __restrict__ HP,
    const float* __restrict__ fW, const float* __restrict__ fb,
    float* __restrict__ out) {
  const int n = blockIdx.y;
  const int t0 = blockIdx.x * 32;
  const int tid = threadIdx.x;
  __shared__ float hp[256][32];
  for (int i = tid; i < 256*32; i += 256) {
    const int c = i / 32, tt = i % 32;
    const int t = t0 + tt;
    hp[c][tt] = (t < 300) ? HP[((size_t)n*256 + c)*300 + t] : 0.f;
  }
  __syncthreads();
  for (int e = tid; e < 60*32; e += 256) {
    const int o = e / 32, tt = e % 32;
    const int t = t0 + tt;
    if (t >= 300) continue;
    float acc = fb[o];
    for (int c = 0; c < 256; ++c) acc += hp[c][tt] * fW[o*256 + c];
    out[((size_t)n*60 + o)*300 + t] = acc;
  }
}

extern "C" void kernel_launch(void* const* d_in, const int* in_sizes, int n_in,
                              void* d_out, int out_size, void* d_ws, size_t ws_size,
                              hipStream_t stream) {
  (void)in_sizes; (void)n_in; (void)out_size; (void)ws_size;
  const float* x     = (const float*)d_in[0];
  const float* A     = (const float*)d_in[1];
  const float* bng   = (const float*)d_in[2];
  const float* bnb   = (const float*)d_in[3];
  const float* finW  = (const float*)d_in[4];
  const float* finb  = (const float*)d_in[5];
  const float* imp0  = (const float*)d_in[6];
  const float* imp1  = (const float*)d_in[7];
  const float* imp2  = (const float*)d_in[8];
  const float* imp3  = (const float*)d_in[9];
  const float* W0    = (const float*)d_in[10];
  const float* g0    = (const float*)d_in[11];
  const float* b0    = (const float*)d_in[12];
  const float* W1    = (const float*)d_in[13];
  const float* g1    = (const float*)d_in[14];
  const float* b1    = (const float*)d_in[15];
  const float* Wr1   = (const float*)d_in[16];
  const float* gr1   = (const float*)d_in[17];
  const float* br1   = (const float*)d_in[18];
  const float* W2    = (const float*)d_in[19];
  const float* g2    = (const float*)d_in[20];
  const float* b2    = (const float*)d_in[21];
  const float* Wr2   = (const float*)d_in[22];
  const float* gr2   = (const float*)d_in[23];
  const float* br2   = (const float*)d_in[24];
  const float* W3    = (const float*)d_in[25];
  const float* g3    = (const float*)d_in[26];
  const float* b3    = (const float*)d_in[27];
  const float* foutW = (const float*)d_in[28];
  const float* foutb = (const float*)d_in[29];
  float* out = (float*)d_out;

  char* base = (char*)d_ws;
  float* Z    = (float*)base;                      // 15,360,000 f32 (61.44 MB)
  u16*   Hmk  = (u16*)base;                        // overlay in Z region
  u16*   BIGU = (u16*)(base + 61440000);           // 46,080,000 u16 (92.16 MB)
  u16*   XA   = BIGU;
  u16*   Rb   = BIGU + 23040000;
  u16*   Hct  = (u16*)(base + 153600000);          // 15,360,000 u16 (30.72 MB)
  float* HP   = (float*)(base + 184320000);        // 614,400 f32
  u16*   WT   = (u16*)(base + 186777600);          // 372,736 u16
  float* Ap   = (float*)(base + 187523072);        // 7,500 f32
  float* ST   = Ap + 7500;
  float* ISC = ST,         *ISH = ST + 80;
  float* BSC = ST + 160,   *BSH = ST + 416;
  float* RSC = ST + 672,   *RSH = ST + 928;
  float* PART = ST + 1200;                         // 4096

  u16* W0t  = WT;            // 64 x 192
  u16* W1t  = WT + 12288;    // 128 x 192
  u16* Wr1t = WT + 36864;    // 128 x 64
  u16* W2t  = WT + 45056;    // 256 x 384
  u16* Wr2t = WT + 143360;   // 256 x 128
  u16* W3t  = WT + 176128;   // 256 x 768

  // ---- prep ----
  k_prep_A<<<30, 256, 0, stream>>>(A, imp0, imp1, imp2, imp3, Ap);
  k_prep_w<<<48,  256, 0, stream>>>(W0,  W0t,  64,  64,  3);
  k_prep_w<<<96,  256, 0, stream>>>(W1,  W1t,  64,  128, 3);
  k_prep_w<<<32,  256, 0, stream>>>(Wr1, Wr1t, 64,  128, 1);
  k_prep_w<<<384, 256, 0, stream>>>(W2,  W2t,  128, 256, 3);
  k_prep_w<<<128, 256, 0, stream>>>(Wr2, Wr2t, 128, 256, 1);
  k_prep_w<<<768, 256, 0, stream>>>(W3,  W3t,  256, 256, 3);

  k_bn_in_stats<<<75, 256, 0, stream>>>(x, bng, bnb, ISC, ISH);
  k_fin<<<dim3(30, 8), 256, 0, stream>>>(x, ISC, ISH, finW, finb, Hct);

  // LDS bytes for k_xa3: (cin*27 + 3*25*28) * 4
  const int lds64  = (64*27  + 2100) * 4;
  const int lds128 = (128*27 + 2100) * 4;
  const int lds256 = (256*27 + 2100) * 4;

  // ---- layer 0: 64 -> 64 ----
  k_xa3<<<dim3(150, 8), 256, lds64, stream>>>(Hct, Ap, XA, nullptr, 64, 6);
  k_gemm<<<dim3(59, 1, 8), 256, 0, stream>>>(XA, W0t, Z, nullptr, 192, 64, 0);
  k_bn_part_win<<<dim3(64, 8), 256, 0, stream>>>(Z, PART, 64);
  k_bn_finalize<<<1, 64, 0, stream>>>(PART, g0, b0, BSC, BSH, 64);
  k_apply<<<8*64, 256, 0, stream>>>(Z, nullptr, nullptr, BSC, BSH, nullptr, nullptr, Hct, 64, 0);

  // ---- layer 1: 64 -> 128 ----
  k_xa3<<<dim3(150, 8), 256, lds64, stream>>>(Hct, Ap + 1875, XA, Hmk, 64, 6);
  k_gemm<<<dim3(59, 2, 8), 256, 0, stream>>>(Hmk, Wr1t, nullptr, Rb, 64, 128, 1);
  k_bn_part_plain<<<dim3(128, 8), 256, 0, stream>>>(Rb, PART, 128);
  k_bn_finalize<<<2, 64, 0, stream>>>(PART, gr1, br1, RSC, RSH, 128);
  k_gemm<<<dim3(59, 2, 8), 256, 0, stream>>>(XA, W1t, Z, nullptr, 192, 128, 0);
  k_bn_part_win<<<dim3(128, 8), 256, 0, stream>>>(Z, PART, 128);
  k_bn_finalize<<<2, 64, 0, stream>>>(PART, g1, b1, BSC, BSH, 128);
  k_apply<<<8*128, 256, 0, stream>>>(Z, Rb, nullptr, BSC, BSH, RSC, RSH, Hct, 128, 1);

  // ---- layer 2: 128 -> 256 ----
  k_xa3<<<dim3(150, 8), 256, lds128, stream>>>(Hct, Ap + 3750, XA, Hmk, 128, 7);
  k_gemm<<<dim3(59, 4, 8), 256, 0, stream>>>(Hmk, Wr2t, nullptr, Rb, 128, 256, 1);
  k_bn_part_plain<<<dim3(256, 8), 256, 0, stream>>>(Rb, PART, 256);
  k_bn_finalize<<<4, 64, 0, stream>>>(PART, gr2, br2, RSC, RSH, 256);
  k_gemm<<<dim3(59, 4, 8), 256, 0, stream>>>(XA, W2t, Z, nullptr, 384, 256, 0);
  k_bn_part_win<<<dim3(256, 8), 256, 0, stream>>>(Z, PART, 256);
  k_bn_finalize<<<4, 64, 0, stream>>>(PART, g2, b2, BSC, BSH, 256);
  k_apply<<<8*256, 256, 0, stream>>>(Z, Rb, nullptr, BSC, BSH, RSC, RSH, Hct, 256, 1);

  // ---- layer 3: 256 -> 256, identity residual ----
  k_xa3<<<dim3(150, 8), 256, lds256, stream>>>(Hct, Ap + 5625, XA, nullptr, 256, 8);
  k_gemm<<<dim3(59, 4, 8), 256, 0, stream>>>(XA, W3t, Z, nullptr, 768, 256, 0);
  k_bn_part_win<<<dim3(256, 8), 256, 0, stream>>>(Z, PART, 256);
  k_bn_finalize<<<4, 64, 0, stream>>>(PART, g3, b3, BSC, BSH, 256);
  k_apply<<<8*256, 256, 0, stream>>>(Z, nullptr, Hct, BSC, BSH, nullptr, nullptr, Hct, 256, 2);

  // ---- head ----
  k_pool<<<2400, 256, 0, stream>>>(Hct, HP);
  k_fout<<<dim3(10, 8), 256, 0, stream>>>(HP, foutW, foutb, out);
}

// Round 6
// 567.271 us; speedup vs baseline: 1.3541x; 1.0216x over previous
//
#include <hip/hip_runtime.h>

#define EPS 1e-5f
typedef unsigned short u16;
typedef __attribute__((ext_vector_type(8))) short short8;
typedef __attribute__((ext_vector_type(4))) float f32x4;

__device__ __forceinline__ float bf2f(u16 u) {
  union { unsigned int i; float f; } c; c.i = ((unsigned int)u) << 16; return c.f;
}
__device__ __forceinline__ u16 f2bf(float f) {
  union { float f; unsigned int i; } c; c.f = f;
  unsigned int u = c.i;
  u += 0x7fffu + ((u >> 16) & 1u);   // round-to-nearest-even
  return (u16)(u >> 16);
}
__device__ __forceinline__ float bits2f(unsigned int b) {
  union { unsigned int i; float f; } c; c.i = b; return c.f;
}
// async global->LDS, 16B per lane; dest = wave-uniform base + lane*16 (linear)
__device__ __forceinline__ void gload16(const u16* g, u16* l) {
  __builtin_amdgcn_global_load_lds(
      (__attribute__((address_space(1))) void*)(void*)g,
      (__attribute__((address_space(3))) void*)l, 16, 0, 0);
}

// ---------- input BN stats: per j = v*3+c over (n,t) ----------
__global__ __launch_bounds__(256) void k_bn_in_stats(const float* __restrict__ x,
    const float* __restrict__ g, const float* __restrict__ b,
    float* __restrict__ iscale, float* __restrict__ ishift) {
  const int j = blockIdx.x;            // 0..74
  const int c = j % 3, v = j / 3;
  const int tid = threadIdx.x;
  float s = 0.f, q = 0.f;
  for (int i = tid; i < 2400; i += 256) {
    const int n = i / 300, t = i % 300;
    const float val = x[(((size_t)n*3 + c)*300 + t)*25 + v];
    s += val; q += val*val;
  }
  __shared__ float rs[256], rq[256];
  rs[tid] = s; rq[tid] = q;
  __syncthreads();
  for (int off = 128; off > 0; off >>= 1) {
    if (tid < off) { rs[tid] += rs[tid+off]; rq[tid] += rq[tid+off]; }
    __syncthreads();
  }
  if (tid == 0) {
    const float mean = rs[0] / 2400.f;
    const float var  = rq[0] / 2400.f - mean*mean;
    const float sc = g[j] * rsqrtf(var + EPS);
    iscale[j] = sc;
    ishift[j] = b[j] - mean*sc;
  }
}

// ---------- fused input-BN apply + fin (3 -> 64), writes bf16 H_ct ----------
__global__ __launch_bounds__(256) void k_fin(const float* __restrict__ x,
    const float* __restrict__ iscale, const float* __restrict__ ishift,
    const float* __restrict__ fW, const float* __restrict__ fb,
    u16* __restrict__ H) {
  const int n = blockIdx.y;
  const int t0 = blockIdx.x * 10;
  const int tid = threadIdx.x;
  __shared__ float xn[3][250];
  __shared__ float wsh[64][3];
  __shared__ float bsh[64];
  if (tid < 192) wsh[tid/3][tid%3] = fW[tid];
  if (tid < 64)  bsh[tid] = fb[tid];
  for (int i = tid; i < 750; i += 256) {
    const int c = i / 250, pos = i % 250;
    const int t = t0 + pos/25, v = pos%25;
    const int j = v*3 + c;
    xn[c][pos] = x[(((size_t)n*3 + c)*300 + t)*25 + v] * iscale[j] + ishift[j];
  }
  __syncthreads();
  for (int e = tid; e < 64*250; e += 256) {
    const int o = e / 250, pos = e % 250;
    float acc = bsh[o]
              + xn[0][pos]*wsh[o][0] + xn[1][pos]*wsh[o][1] + xn[2][pos]*wsh[o][2];
    const int t = t0 + pos/25, v = pos%25;
    H[(((size_t)n*64 + o)*300 + t)*25 + v] = f2bf(acc);
  }
}

// ---------- prep: A' = A * imp per layer (fp32) ----------
__global__ void k_prep_A(const float* __restrict__ A,
    const float* __restrict__ i0, const float* __restrict__ i1,
    const float* __restrict__ i2, const float* __restrict__ i3,
    float* __restrict__ Ap) {
  const int idx = blockIdx.x*256 + threadIdx.x;
  if (idx >= 7500) return;
  const int layer = idx / 1875, r = idx % 1875;
  const int vw = r % 625;
  const float* imp = (layer==0) ? i0 : (layer==1) ? i1 : (layer==2) ? i2 : i3;
  Ap[idx] = A[r] * imp[vw];
}

// ---------- prep: Wt[co][p*cin+ci] = bf16(W[(p*cout+co)*cin+ci]) ----------
__global__ void k_prep_w(const float* __restrict__ W, u16* __restrict__ Wt,
    int cin, int cout, int P) {
  const int idx = blockIdx.x*256 + threadIdx.x;
  const int K = P*cin;
  if (idx >= cout*K) return;
  const int co = idx / K, k = idx % K;
  const int p = k / cin, ci = k % cin;
  Wt[idx] = f2bf(W[((size_t)(p*cout + co))*cin + ci]);
}

// ---------- xa3: XA[m=(n,t,w)][p*cin+ci] = sum_v H[ci][t][v] * A'[p][v][w] ----------
__global__ __launch_bounds__(256) void k_xa3(const u16* __restrict__ H,
    const float* __restrict__ Ap, u16* __restrict__ XA, u16* Hmk,
    int cin, int log2cin) {
  const int t0 = blockIdx.x * 2;       // 150 t-pairs
  const int n  = blockIdx.y;
  const int tid = threadIdx.x;
  const int K = 3 * cin;
  extern __shared__ unsigned int xs[]; // [cin][27] packed x ; then A' [3][25][28] floats
  float* As = (float*)(xs + cin*27);

  for (int i = tid; i < 1875; i += 256) {
    const int p = i / 625, r = i % 625;
    As[p*700 + (r/25)*28 + (r%25)] = Ap[i];
  }
  for (int idx = tid; idx < cin*25; idx += 256) {
    const int ci = idx / 25, c = idx % 25;
    const char* src = (const char*)H + ((((size_t)n*cin + ci)*7500) + (size_t)t0*25)*2 + c*4;
    xs[ci*27 + c] = *(const unsigned int*)src;
  }
  __syncthreads();

  for (int kc = 0; kc < K; kc += 256) {
    const int k = kc + tid;
    if (k < K) {
      const int ci = k & (cin - 1);
      const int p  = k >> log2cin;     // wave-uniform
      const float* __restrict__ Ab = &As[p*700];

      unsigned int raw[25];
      #pragma unroll
      for (int j = 0; j < 25; ++j) raw[j] = xs[ci*27 + j];

      float acc0[25], acc1[25];
      #pragma unroll
      for (int w = 0; w < 25; ++w) { acc0[w] = 0.f; acc1[w] = 0.f; }

      #pragma unroll
      for (int v = 0; v < 25; ++v) {
        const int e1 = 25 + v;
        const float xv0 = bits2f((v & 1)  ? (raw[v  >> 1] & 0xffff0000u)
                                          : (raw[v  >> 1] << 16));
        const float xv1 = bits2f((e1 & 1) ? (raw[e1 >> 1] & 0xffff0000u)
                                          : (raw[e1 >> 1] << 16));
        #pragma unroll
        for (int j = 0; j < 7; ++j) {
          const f32x4 a = *(const f32x4*)&Ab[v*28 + j*4];  // uniform addr -> broadcast
          #pragma unroll
          for (int e = 0; e < 4; ++e) {
            const int w = j*4 + e;
            if (w < 25) {
              acc0[w] = fmaf(a[e], xv0, acc0[w]);
              acc1[w] = fmaf(a[e], xv1, acc1[w]);
            }
          }
        }
      }

      const size_t mb0 = ((size_t)n*300 + t0)*25;
      #pragma unroll
      for (int w = 0; w < 25; ++w) XA[(mb0 + w)*K + k]      = f2bf(acc0[w]);
      #pragma unroll
      for (int w = 0; w < 25; ++w) XA[(mb0 + 25 + w)*K + k] = f2bf(acc1[w]);

      if (Hmk && p == 0) {
        #pragma unroll
        for (int v = 0; v < 25; ++v) {
          const unsigned int b0 = (v & 1) ? (raw[v >> 1] >> 16) : (raw[v >> 1] & 0xffffu);
          Hmk[(mb0 + v)*cin + ci] = (u16)b0;
        }
        #pragma unroll
        for (int v = 0; v < 25; ++v) {
          const int e = 25 + v;
          const unsigned int b1 = (e & 1) ? (raw[e >> 1] >> 16) : (raw[e >> 1] & 0xffffu);
          Hmk[(mb0 + 25 + v)*cin + ci] = (u16)b1;
        }
      }
    }
  }
}

// ---------- bf16 MFMA GEMM (flattened M=60000) ----------
// A: bf16 [60000][K] (k contiguous); B: bf16 [N][K]; C: bf16 [co][60000]
// Staging via global_load_lds (linear LDS dest, pre-swizzled global source).
__global__ __launch_bounds__(256) void k_gemm(const u16* __restrict__ Asrc,
    const u16* __restrict__ Bsrc, u16* __restrict__ Cb, int K) {
  const int n0b = blockIdx.x * 64;
  const int m0  = blockIdx.y * 128;
  const int tid = threadIdx.x;
  const int lane = tid & 63, wid = tid >> 6;
  const int wm = (wid & 1) * 64, wn = (wid >> 1) * 32;

  __shared__ u16 As[128*64];
  __shared__ u16 Bs[64*64];

  f32x4 acc[4][2];
  #pragma unroll
  for (int mi = 0; mi < 4; ++mi)
    #pragma unroll
    for (int ni = 0; ni < 2; ++ni) acc[mi][ni] = (f32x4){0.f,0.f,0.f,0.f};

  // per-thread staging indices (linear LDS dest; XOR-swizzled global chunk)
  const int rA = tid >> 3, cA = tid & 7;

  const int nkt = K >> 6;
  for (int kt = 0; kt < nkt; ++kt) {
    const int kbase = kt * 64;
    __syncthreads();   // all waves done reading previous tile
    #pragma unroll
    for (int i = 0; i < 4; ++i) {
      const int idx = tid + i*256;            // 0..1023
      const int r = rA + i*32;                // idx>>3
      int m = m0 + r; if (m > 59999) m = 59999;
      gload16(Asrc + (size_t)m*K + kbase + ((cA ^ (r & 7)) * 8), &As[idx*8]);
    }
    #pragma unroll
    for (int i = 0; i < 2; ++i) {
      const int idx = tid + i*256;            // 0..511
      const int r = rA + i*32;
      gload16(Bsrc + (size_t)(n0b + r)*K + kbase + ((cA ^ (r & 7)) * 8), &Bs[idx*8]);
    }
    __syncthreads();   // drains vmcnt(0) -> tile ready
    #pragma unroll
    for (int kc = 0; kc < 2; ++kc) {
      const int kchunk = kc*4 + (lane >> 4);
      short8 a[4], b[2];
      #pragma unroll
      for (int mi = 0; mi < 4; ++mi) {
        const int m = wm + mi*16 + (lane & 15);
        a[mi] = *(const short8*)&As[m*64 + ((kchunk ^ (m & 7)) * 8)];
      }
      #pragma unroll
      for (int ni = 0; ni < 2; ++ni) {
        const int r = wn + ni*16 + (lane & 15);
        b[ni] = *(const short8*)&Bs[r*64 + ((kchunk ^ (r & 7)) * 8)];
      }
      #pragma unroll
      for (int mi = 0; mi < 4; ++mi)
        #pragma unroll
        for (int ni = 0; ni < 2; ++ni)
          acc[mi][ni] = __builtin_amdgcn_mfma_f32_16x16x32_bf16(a[mi], b[ni], acc[mi][ni], 0, 0, 0);
    }
  }

  const int mrow = (lane >> 4) * 4;
  #pragma unroll
  for (int mi = 0; mi < 4; ++mi) {
    const int mb = m0 + wm + mi*16 + mrow;
    if (mb >= 60000) continue;
    #pragma unroll
    for (int ni = 0; ni < 2; ++ni) {
      const int co = n0b + wn + ni*16 + (lane & 15);
      unsigned long long pk =
          (unsigned long long)f2bf(acc[mi][ni][0]) |
          ((unsigned long long)f2bf(acc[mi][ni][1]) << 16) |
          ((unsigned long long)f2bf(acc[mi][ni][2]) << 32) |
          ((unsigned long long)f2bf(acc[mi][ni][3]) << 48);
      *(unsigned long long*)&Cb[(size_t)co*60000 + mb] = pk;
    }
  }
}

// ---------- BN partial stats of windowed sum S (bf16 Z, [co][60000]), per (c,n) ----------
__global__ __launch_bounds__(256) void k_bn_part_win(const u16* __restrict__ G,
    float* __restrict__ part, int cout) {
  const int c = blockIdx.x, n = blockIdx.y;
  const int tid = threadIdx.x;
  const u16* gb = G + (size_t)c*60000 + (size_t)n*7500;
  float s = 0.f, q = 0.f;
  for (int i = tid; i < 7500; i += 256) {
    const int ss = i / 25, w = i % 25;
    float S = 0.f;
    if (ss >= 8) {
      #pragma unroll
      for (int d = 0; d < 9; ++d) S += bf2f(gb[i - d*25]);
    } else {
      for (int tt = 0; tt <= ss; ++tt) S += bf2f(gb[tt*25 + w]);
    }
    s += S; q += S*S;
  }
  __shared__ float rs[256], rq[256];
  rs[tid] = s; rq[tid] = q;
  __syncthreads();
  for (int off = 128; off > 0; off >>= 1) {
    if (tid < off) { rs[tid] += rs[tid+off]; rq[tid] += rq[tid+off]; }
    __syncthreads();
  }
  if (tid == 0) {
    part[((size_t)c*8 + n)*2]     = rs[0];
    part[((size_t)c*8 + n)*2 + 1] = rq[0];
  }
}

// ---------- BN partial stats, plain (bf16 R, [co][60000]) ----------
__global__ __launch_bounds__(256) void k_bn_part_plain(const u16* __restrict__ R,
    float* __restrict__ part, int cout) {
  const int c = blockIdx.x, n = blockIdx.y;
  const int tid = threadIdx.x;
  const u16* rb = R + (size_t)c*60000 + (size_t)n*7500;
  float s = 0.f, q = 0.f;
  for (int i = tid; i < 7500; i += 256) {
    const float val = bf2f(rb[i]);
    s += val; q += val*val;
  }
  __shared__ float rs[256], rq[256];
  rs[tid] = s; rq[tid] = q;
  __syncthreads();
  for (int off = 128; off > 0; off >>= 1) {
    if (tid < off) { rs[tid] += rs[tid+off]; rq[tid] += rq[tid+off]; }
    __syncthreads();
  }
  if (tid == 0) {
    part[((size_t)c*8 + n)*2]     = rs[0];
    part[((size_t)c*8 + n)*2 + 1] = rq[0];
  }
}

// ---------- finalize BN ----------
__global__ void k_bn_finalize(const float* __restrict__ part,
    const float* __restrict__ g, const float* __restrict__ b,
    float* __restrict__ scale, float* __restrict__ shift, int cout) {
  const int c = blockIdx.x * 64 + threadIdx.x;
  if (c >= cout) return;
  float s = 0.f, q = 0.f;
  for (int n = 0; n < 8; ++n) {
    s += part[((size_t)c*8 + n)*2];
    q += part[((size_t)c*8 + n)*2 + 1];
  }
  const float mean = s / 60000.f;
  const float var  = q / 60000.f - mean*mean;
  const float sc = g[c] * rsqrtf(var + EPS);
  scale[c] = sc;
  shift[c] = b[c] - mean*sc;
}

// ---------- fused window-sum + BN + relu + residual; writes bf16 H ----------
// Z,R are [co][60000] bf16; Hres/Out are [n][c][t][v] bf16.
__global__ __launch_bounds__(256) void k_apply(const u16* __restrict__ G,
    const u16* __restrict__ Rb, const u16* Hres,
    const float* __restrict__ scale, const float* __restrict__ shift,
    const float* __restrict__ rscale, const float* __restrict__ rshift,
    u16* Out, int cout, int mode) {
  const int bc = blockIdx.x;          // n*cout + c
  const int c = bc % cout, n = bc / cout;
  const u16* gb = G + (size_t)c*60000 + (size_t)n*7500;
  const float sc = scale[c], sh = shift[c];
  float rsc = 0.f, rsh = 0.f;
  if (mode == 1) { rsc = rscale[c]; rsh = rshift[c]; }
  const size_t rbase = (size_t)c*60000 + (size_t)n*7500;
  for (int i = threadIdx.x; i < 7500; i += 256) {
    const int ss = i / 25, w = i % 25;
    float S = 0.f;
    if (ss >= 8) {
      #pragma unroll
      for (int d = 0; d < 9; ++d) S += bf2f(gb[i - d*25]);
    } else {
      for (int tt = 0; tt <= ss; ++tt) S += bf2f(gb[tt*25 + w]);
    }
    const float h = fmaxf(S*sc + sh, 0.f);
    float o;
    if (mode == 0)      o = h;
    else if (mode == 1) o = fmaxf(h + (bf2f(Rb[rbase + i])*rsc + rsh), 0.f);
    else                o = fmaxf(h + bf2f(Hres[(size_t)bc*7500 + i]), 0.f);
    Out[(size_t)bc*7500 + i] = f2bf(o);
  }
}

// ---------- mean pool over joints (bf16 in, fp32 out) ----------
__global__ void k_pool(const u16* __restrict__ H, float* __restrict__ HP) {
  const int idx = blockIdx.x*256 + threadIdx.x;
  if (idx >= 8*256*300) return;
  const u16* base = H + (size_t)idx * 25;
  float s = 0.f;
  #pragma unroll
  for (int v = 0; v < 25; ++v) s += bf2f(base[v]);
  HP[idx] = s * (1.f/25.f);
}

// ---------- classifier conv ----------
__global__ __launch_bounds__(256) void k_fout(const float* __restrict__ HP,
    const float* __restrict__ fW, const float* __restrict__ fb,
    float* __restrict__ out) {
  const int n = blockIdx.y;
  const int t0 = blockIdx.x * 32;
  const int tid = threadIdx.x;
  __shared__ float hp[256][32];
  for (int i = tid; i < 256*32; i += 256) {
    const int c = i / 32, tt = i % 32;
    const int t = t0 + tt;
    hp[c][tt] = (t < 300) ? HP[((size_t)n*256 + c)*300 + t] : 0.f;
  }
  __syncthreads();
  for (int e = tid; e < 60*32; e += 256) {
    const int o = e / 32, tt = e % 32;
    const int t = t0 + tt;
    if (t >= 300) continue;
    float acc = fb[o];
    for (int c = 0; c < 256; ++c) acc += hp[c][tt] * fW[o*256 + c];
    out[((size_t)n*60 + o)*300 + t] = acc;
  }
}

extern "C" void kernel_launch(void* const* d_in, const int* in_sizes, int n_in,
                              void* d_out, int out_size, void* d_ws, size_t ws_size,
                              hipStream_t stream) {
  (void)in_sizes; (void)n_in; (void)out_size; (void)ws_size;
  const float* x     = (const float*)d_in[0];
  const float* A     = (const float*)d_in[1];
  const float* bng   = (const float*)d_in[2];
  const float* bnb   = (const float*)d_in[3];
  const float* finW  = (const float*)d_in[4];
  const float* finb  = (const float*)d_in[5];
  const float* imp0  = (const float*)d_in[6];
  const float* imp1  = (const float*)d_in[7];
  const float* imp2  = (const float*)d_in[8];
  const float* imp3  = (const float*)d_in[9];
  const float* W0    = (const float*)d_in[10];
  const float* g0    = (const float*)d_in[11];
  const float* b0    = (const float*)d_in[12];
  const float* W1    = (const float*)d_in[13];
  const float* g1    = (const float*)d_in[14];
  const float* b1    = (const float*)d_in[15];
  const float* Wr1   = (const float*)d_in[16];
  const float* gr1   = (const float*)d_in[17];
  const float* br1   = (const float*)d_in[18];
  const float* W2    = (const float*)d_in[19];
  const float* g2    = (const float*)d_in[20];
  const float* b2    = (const float*)d_in[21];
  const float* Wr2   = (const float*)d_in[22];
  const float* gr2   = (const float*)d_in[23];
  const float* br2   = (const float*)d_in[24];
  const float* W3    = (const float*)d_in[25];
  const float* g3    = (const float*)d_in[26];
  const float* b3    = (const float*)d_in[27];
  const float* foutW = (const float*)d_in[28];
  const float* foutb = (const float*)d_in[29];
  float* out = (float*)d_out;

  char* base = (char*)d_ws;
  u16*   Z    = (u16*)base;                        // bf16 [co][60000] (<=30.72 MB of 61.44 region)
  u16*   Hmk  = (u16*)base;                        // overlay (dead before Z written)
  u16*   BIGU = (u16*)(base + 61440000);
  u16*   XA   = BIGU;                              // bf16 [60000][K]
  u16*   Rb   = BIGU + 23040000;                   // bf16 [co][60000]
  u16*   Hct  = (u16*)(base + 153600000);          // bf16 [n][c][t][v]
  float* HP   = (float*)(base + 184320000);
  u16*   WT   = (u16*)(base + 186777600);
  float* Ap   = (float*)(base + 187523072);
  float* ST   = Ap + 7500;
  float* ISC = ST,         *ISH = ST + 80;
  float* BSC = ST + 160,   *BSH = ST + 416;
  float* RSC = ST + 672,   *RSH = ST + 928;
  float* PART = ST + 1200;

  u16* W0t  = WT;            // 64 x 192
  u16* W1t  = WT + 12288;    // 128 x 192
  u16* Wr1t = WT + 36864;    // 128 x 64
  u16* W2t  = WT + 45056;    // 256 x 384
  u16* Wr2t = WT + 143360;   // 256 x 128
  u16* W3t  = WT + 176128;   // 256 x 768

  // ---- prep ----
  k_prep_A<<<30, 256, 0, stream>>>(A, imp0, imp1, imp2, imp3, Ap);
  k_prep_w<<<48,  256, 0, stream>>>(W0,  W0t,  64,  64,  3);
  k_prep_w<<<96,  256, 0, stream>>>(W1,  W1t,  64,  128, 3);
  k_prep_w<<<32,  256, 0, stream>>>(Wr1, Wr1t, 64,  128, 1);
  k_prep_w<<<384, 256, 0, stream>>>(W2,  W2t,  128, 256, 3);
  k_prep_w<<<128, 256, 0, stream>>>(Wr2, Wr2t, 128, 256, 1);
  k_prep_w<<<768, 256, 0, stream>>>(W3,  W3t,  256, 256, 3);

  k_bn_in_stats<<<75, 256, 0, stream>>>(x, bng, bnb, ISC, ISH);
  k_fin<<<dim3(30, 8), 256, 0, stream>>>(x, ISC, ISH, finW, finb, Hct);

  const int lds64  = (64*27  + 2100) * 4;
  const int lds128 = (128*27 + 2100) * 4;
  const int lds256 = (256*27 + 2100) * 4;
  const int MT = 469;   // ceil(60000/128)

  // ---- layer 0: 64 -> 64 ----
  k_xa3<<<dim3(150, 8), 256, lds64, stream>>>(Hct, Ap, XA, nullptr, 64, 6);
  k_gemm<<<dim3(1, MT), 256, 0, stream>>>(XA, W0t, Z, 192);
  k_bn_part_win<<<dim3(64, 8), 256, 0, stream>>>(Z, PART, 64);
  k_bn_finalize<<<1, 64, 0, stream>>>(PART, g0, b0, BSC, BSH, 64);
  k_apply<<<8*64, 256, 0, stream>>>(Z, nullptr, nullptr, BSC, BSH, nullptr, nullptr, Hct, 64, 0);

  // ---- layer 1: 64 -> 128 ----
  k_xa3<<<dim3(150, 8), 256, lds64, stream>>>(Hct, Ap + 1875, XA, Hmk, 64, 6);
  k_gemm<<<dim3(2, MT), 256, 0, stream>>>(Hmk, Wr1t, Rb, 64);
  k_bn_part_plain<<<dim3(128, 8), 256, 0, stream>>>(Rb, PART, 128);
  k_bn_finalize<<<2, 64, 0, stream>>>(PART, gr1, br1, RSC, RSH, 128);
  k_gemm<<<dim3(2, MT), 256, 0, stream>>>(XA, W1t, Z, 192);
  k_bn_part_win<<<dim3(128, 8), 256, 0, stream>>>(Z, PART, 128);
  k_bn_finalize<<<2, 64, 0, stream>>>(PART, g1, b1, BSC, BSH, 128);
  k_apply<<<8*128, 256, 0, stream>>>(Z, Rb, nullptr, BSC, BSH, RSC, RSH, Hct, 128, 1);

  // ---- layer 2: 128 -> 256 ----
  k_xa3<<<dim3(150, 8), 256, lds128, stream>>>(Hct, Ap + 3750, XA, Hmk, 128, 7);
  k_gemm<<<dim3(4, MT), 256, 0, stream>>>(Hmk, Wr2t, Rb, 128);
  k_bn_part_plain<<<dim3(256, 8), 256, 0, stream>>>(Rb, PART, 256);
  k_bn_finalize<<<4, 64, 0, stream>>>(PART, gr2, br2, RSC, RSH, 256);
  k_gemm<<<dim3(4, MT), 256, 0, stream>>>(XA, W2t, Z, 384);
  k_bn_part_win<<<dim3(256, 8), 256, 0, stream>>>(Z, PART, 256);
  k_bn_finalize<<<4, 64, 0, stream>>>(PART, g2, b2, BSC, BSH, 256);
  k_apply<<<8*256, 256, 0, stream>>>(Z, Rb, nullptr, BSC, BSH, RSC, RSH, Hct, 256, 1);

  // ---- layer 3: 256 -> 256, identity residual ----
  k_xa3<<<dim3(150, 8), 256, lds256, stream>>>(Hct, Ap + 5625, XA, nullptr, 256, 8);
  k_gemm<<<dim3(4, MT), 256, 0, stream>>>(XA, W3t, Z, 768);
  k_bn_part_win<<<dim3(256, 8), 256, 0, stream>>>(Z, PART, 256);
  k_bn_finalize<<<4, 64, 0, stream>>>(PART, g3, b3, BSC, BSH, 256);
  k_apply<<<8*256, 256, 0, stream>>>(Z, nullptr, Hct, BSC, BSH, nullptr, nullptr, Hct, 256, 2);

  // ---- head ----
  k_pool<<<2400, 256, 0, stream>>>(Hct, HP);
  k_fout<<<dim3(10, 8), 256, 0, stream>>>(HP, foutW, foutb, out);
}

// Round 7
// 480.710 us; speedup vs baseline: 1.5979x; 1.1801x over previous
//
#include <hip/hip_runtime.h>

#define EPS 1e-5f
typedef unsigned short u16;
typedef __attribute__((ext_vector_type(8))) short short8;
typedef __attribute__((ext_vector_type(4))) float f32x4;

__device__ __forceinline__ float bf2f(u16 u) {
  union { unsigned int i; float f; } c; c.i = ((unsigned int)u) << 16; return c.f;
}
__device__ __forceinline__ u16 f2bf(float f) {
  union { float f; unsigned int i; } c; c.f = f;
  unsigned int u = c.i;
  u += 0x7fffu + ((u >> 16) & 1u);   // round-to-nearest-even
  return (u16)(u >> 16);
}
__device__ __forceinline__ float bits2f(unsigned int b) {
  union { unsigned int i; float f; } c; c.i = b; return c.f;
}
__device__ __forceinline__ unsigned int cvt_pk_bf16(float lo, float hi) {
  unsigned int r;
  asm("v_cvt_pk_bf16_f32 %0, %1, %2" : "=v"(r) : "v"(lo), "v"(hi));
  return r;
}
// unaligned-safe 16B load (H rows are 50B-strided)
__device__ __forceinline__ short8 load8u(const u16* p) {
  short8 v; __builtin_memcpy(&v, p, 16); return v;
}
// async global->LDS, 16B per lane; dest = wave-uniform base + lane*16 (linear)
__device__ __forceinline__ void gload16(const u16* g, u16* l) {
  __builtin_amdgcn_global_load_lds(
      (__attribute__((address_space(1))) void*)(void*)g,
      (__attribute__((address_space(3))) void*)l, 16, 0, 0);
}

// ---------- merged prep: Ap, 6 weight transposes, ATb, Hct end-pad ----------
__device__ __forceinline__ void prep_w_elem(const float* W, u16* Wt,
    int cin, int cout, int P, int idx) {
  const int K = P*cin;
  const int co = idx / K, k = idx % K;
  const int p = k / cin, ci = k % cin;
  Wt[idx] = f2bf(W[((size_t)(p*cout + co))*cin + ci]);
}

__global__ __launch_bounds__(256) void k_prep_all(
    const float* __restrict__ A,
    const float* __restrict__ i0, const float* __restrict__ i1,
    const float* __restrict__ i2, const float* __restrict__ i3,
    const float* __restrict__ W0, const float* __restrict__ W1,
    const float* __restrict__ Wr1, const float* __restrict__ W2,
    const float* __restrict__ Wr2, const float* __restrict__ W3,
    float* __restrict__ Ap, u16* W0t, u16* W1t, u16* Wr1t, u16* W2t,
    u16* Wr2t, u16* W3t, u16* ATb, u16* hpad) {
  int idx = blockIdx.x*256 + threadIdx.x;
  if (idx < 7500) {                      // Ap (fp32 A*imp, used by xa3)
    const int layer = idx / 1875, r = idx % 1875;
    const int vw = r % 625;
    const float* imp = (layer==0)?i0:(layer==1)?i1:(layer==2)?i2:i3;
    Ap[idx] = A[r] * imp[vw];
    return;
  }
  idx -= 7500;
  if (idx < 12288) { prep_w_elem(W0,  W0t,  64,  64,  3, idx); return; }
  idx -= 12288;
  if (idx < 24576) { prep_w_elem(W1,  W1t,  64,  128, 3, idx); return; }
  idx -= 24576;
  if (idx < 8192)  { prep_w_elem(Wr1, Wr1t, 64,  128, 1, idx); return; }
  idx -= 8192;
  if (idx < 98304) { prep_w_elem(W2,  W2t,  128, 256, 3, idx); return; }
  idx -= 98304;
  if (idx < 32768) { prep_w_elem(Wr2, Wr2t, 128, 256, 1, idx); return; }
  idx -= 32768;
  if (idx < 196608){ prep_w_elem(W3,  W3t,  256, 256, 3, idx); return; }
  idx -= 196608;
  if (idx < 12288) {                     // ATb[l][p][w(32)][v(32)] = bf16(A'[p][v][w]), zero-padded
    const int l = idx / 3072, r = idx % 3072;
    const int p = r / 1024, wv = r % 1024;
    const int w = wv >> 5, v = wv & 31;
    float val = 0.f;
    if (w < 25 && v < 25) {
      const float* imp = (l==0)?i0:(l==1)?i1:(l==2)?i2:i3;
      val = A[(p*25 + v)*25 + w] * imp[v*25 + w];
    }
    ATb[idx] = f2bf(val);
    return;
  }
  idx -= 12288;
  if (idx < 32) hpad[idx] = 0;           // safe overhang for xa_mfma A-frags
}

// ---------- input BN stats: per j = v*3+c over (n,t) ----------
__global__ __launch_bounds__(256) void k_bn_in_stats(const float* __restrict__ x,
    const float* __restrict__ g, const float* __restrict__ b,
    float* __restrict__ iscale, float* __restrict__ ishift) {
  const int j = blockIdx.x;            // 0..74
  const int c = j % 3, v = j / 3;
  const int tid = threadIdx.x;
  float s = 0.f, q = 0.f;
  for (int i = tid; i < 2400; i += 256) {
    const int n = i / 300, t = i % 300;
    const float val = x[(((size_t)n*3 + c)*300 + t)*25 + v];
    s += val; q += val*val;
  }
  __shared__ float rs[256], rq[256];
  rs[tid] = s; rq[tid] = q;
  __syncthreads();
  for (int off = 128; off > 0; off >>= 1) {
    if (tid < off) { rs[tid] += rs[tid+off]; rq[tid] += rq[tid+off]; }
    __syncthreads();
  }
  if (tid == 0) {
    const float mean = rs[0] / 2400.f;
    const float var  = rq[0] / 2400.f - mean*mean;
    const float sc = g[j] * rsqrtf(var + EPS);
    iscale[j] = sc;
    ishift[j] = b[j] - mean*sc;
  }
}

// ---------- fused input-BN apply + fin (3 -> 64), writes bf16 H_ct ----------
__global__ __launch_bounds__(256) void k_fin(const float* __restrict__ x,
    const float* __restrict__ iscale, const float* __restrict__ ishift,
    const float* __restrict__ fW, const float* __restrict__ fb,
    u16* __restrict__ H) {
  const int n = blockIdx.y;
  const int t0 = blockIdx.x * 10;
  const int tid = threadIdx.x;
  __shared__ float xn[3][250];
  __shared__ float wsh[64][3];
  __shared__ float bsh[64];
  if (tid < 192) wsh[tid/3][tid%3] = fW[tid];
  if (tid < 64)  bsh[tid] = fb[tid];
  for (int i = tid; i < 750; i += 256) {
    const int c = i / 250, pos = i % 250;
    const int t = t0 + pos/25, v = pos%25;
    const int j = v*3 + c;
    xn[c][pos] = x[(((size_t)n*3 + c)*300 + t)*25 + v] * iscale[j] + ishift[j];
  }
  __syncthreads();
  for (int e = tid; e < 64*250; e += 256) {
    const int o = e / 250, pos = e % 250;
    float acc = bsh[o]
              + xn[0][pos]*wsh[o][0] + xn[1][pos]*wsh[o][1] + xn[2][pos]*wsh[o][2];
    const int t = t0 + pos/25, v = pos%25;
    H[(((size_t)n*64 + o)*300 + t)*25 + v] = f2bf(acc);
  }
}

// ---------- xa via MFMA (layers without Hmk): ----------
// XA[(n,t,w)][p*cin+ci] = sum_v H[ci][t][v] * AT[p][w][v]
// A-operand = H rows(ci), k=v (v-contiguous in Hct); B-operand = AT rows(w), k=v.
// AT zero-padded at v>=25 annihilates the 7-element v-overhang read.
__global__ __launch_bounds__(256) void k_xa_mfma(const u16* __restrict__ H,
    const u16* __restrict__ ATl, u16* __restrict__ XA, int cin, int K) {
  const int lane = threadIdx.x & 63, wid = threadIdx.x >> 6;
  const int t = blockIdx.x * 4 + wid;      // 4 waves = 4 timesteps per block
  const int n = blockIdx.y;
  const int lrow = lane & 15, lchunk = lane >> 4;
  short8 bf[3][2];
  #pragma unroll
  for (int p = 0; p < 3; ++p)
    #pragma unroll
    for (int wt = 0; wt < 2; ++wt)
      bf[p][wt] = *(const short8*)&ATl[(p*32 + wt*16 + lrow)*32 + lchunk*8];
  const int ntile = cin >> 4;
  const size_t mrow0 = ((size_t)n*300 + t)*25;
  const int ciq = lchunk*4;
  for (int citile = 0; citile < ntile; ++citile) {
    const int ci = citile*16 + lrow;
    const short8 af = load8u(&H[((size_t)(n*cin + ci)*300 + t)*25 + lchunk*8]);
    #pragma unroll
    for (int p = 0; p < 3; ++p) {
      #pragma unroll
      for (int wt = 0; wt < 2; ++wt) {
        f32x4 acc = (f32x4){0.f, 0.f, 0.f, 0.f};
        acc = __builtin_amdgcn_mfma_f32_16x16x32_bf16(af, bf[p][wt], acc, 0, 0, 0);
        const int w = wt*16 + lrow;
        if (w < 25) {
          uint2 pk;
          pk.x = cvt_pk_bf16(acc[0], acc[1]);
          pk.y = cvt_pk_bf16(acc[2], acc[3]);
          *(uint2*)&XA[(mrow0 + w)*K + p*cin + citile*16 + ciq] = pk;
        }
      }
    }
  }
}

// ---------- xa3 (VALU, produces Hmk for residual layers 1,2) ----------
__global__ __launch_bounds__(256) void k_xa3(const u16* __restrict__ H,
    const float* __restrict__ Ap, u16* __restrict__ XA, u16* Hmk,
    int cin, int log2cin) {
  const int t0 = blockIdx.x * 2;
  const int n  = blockIdx.y;
  const int tid = threadIdx.x;
  const int K = 3 * cin;
  extern __shared__ unsigned int xs[];
  float* As = (float*)(xs + cin*27);

  for (int i = tid; i < 1875; i += 256) {
    const int p = i / 625, r = i % 625;
    As[p*700 + (r/25)*28 + (r%25)] = Ap[i];
  }
  for (int idx = tid; idx < cin*25; idx += 256) {
    const int ci = idx / 25, c = idx % 25;
    const char* src = (const char*)H + ((((size_t)n*cin + ci)*7500) + (size_t)t0*25)*2 + c*4;
    xs[ci*27 + c] = *(const unsigned int*)src;
  }
  __syncthreads();

  for (int kc = 0; kc < K; kc += 256) {
    const int k = kc + tid;
    if (k < K) {
      const int ci = k & (cin - 1);
      const int p  = k >> log2cin;
      const float* __restrict__ Ab = &As[p*700];

      unsigned int raw[25];
      #pragma unroll
      for (int j = 0; j < 25; ++j) raw[j] = xs[ci*27 + j];

      float acc0[25], acc1[25];
      #pragma unroll
      for (int w = 0; w < 25; ++w) { acc0[w] = 0.f; acc1[w] = 0.f; }

      #pragma unroll
      for (int v = 0; v < 25; ++v) {
        const int e1 = 25 + v;
        const float xv0 = bits2f((v & 1)  ? (raw[v  >> 1] & 0xffff0000u)
                                          : (raw[v  >> 1] << 16));
        const float xv1 = bits2f((e1 & 1) ? (raw[e1 >> 1] & 0xffff0000u)
                                          : (raw[e1 >> 1] << 16));
        #pragma unroll
        for (int j = 0; j < 7; ++j) {
          const f32x4 a = *(const f32x4*)&Ab[v*28 + j*4];
          #pragma unroll
          for (int e = 0; e < 4; ++e) {
            const int w = j*4 + e;
            if (w < 25) {
              acc0[w] = fmaf(a[e], xv0, acc0[w]);
              acc1[w] = fmaf(a[e], xv1, acc1[w]);
            }
          }
        }
      }

      const size_t mb0 = ((size_t)n*300 + t0)*25;
      #pragma unroll
      for (int w = 0; w < 25; ++w) XA[(mb0 + w)*K + k]      = f2bf(acc0[w]);
      #pragma unroll
      for (int w = 0; w < 25; ++w) XA[(mb0 + 25 + w)*K + k] = f2bf(acc1[w]);

      if (p == 0) {
        #pragma unroll
        for (int v = 0; v < 25; ++v) {
          const unsigned int b0 = (v & 1) ? (raw[v >> 1] >> 16) : (raw[v >> 1] & 0xffffu);
          Hmk[(mb0 + v)*cin + ci] = (u16)b0;
        }
        #pragma unroll
        for (int v = 0; v < 25; ++v) {
          const int e = 25 + v;
          const unsigned int b1 = (e & 1) ? (raw[e >> 1] >> 16) : (raw[e >> 1] & 0xffffu);
          Hmk[(mb0 + 25 + v)*cin + ci] = (u16)b1;
        }
      }
    }
  }
}

// ---------- bf16 MFMA GEMM, 128x64 tile (N=64/128) ----------
__global__ __launch_bounds__(256) void k_gemm(const u16* __restrict__ Asrc,
    const u16* __restrict__ Bsrc, u16* __restrict__ Cb, int K) {
  const int n0b = blockIdx.x * 64;
  const int m0  = blockIdx.y * 128;
  const int tid = threadIdx.x;
  const int lane = tid & 63, wid = tid >> 6;
  const int wm = (wid & 1) * 64, wn = (wid >> 1) * 32;

  __shared__ u16 As[128*64];
  __shared__ u16 Bs[64*64];

  f32x4 acc[4][2];
  #pragma unroll
  for (int mi = 0; mi < 4; ++mi)
    #pragma unroll
    for (int ni = 0; ni < 2; ++ni) acc[mi][ni] = (f32x4){0.f,0.f,0.f,0.f};

  const int rA = tid >> 3, cA = tid & 7;

  const int nkt = K >> 6;
  for (int kt = 0; kt < nkt; ++kt) {
    const int kbase = kt * 64;
    __syncthreads();
    #pragma unroll
    for (int i = 0; i < 4; ++i) {
      const int idx = tid + i*256;
      const int r = rA + i*32;
      int m = m0 + r; if (m > 59999) m = 59999;
      gload16(Asrc + (size_t)m*K + kbase + ((cA ^ (r & 7)) * 8), &As[idx*8]);
    }
    #pragma unroll
    for (int i = 0; i < 2; ++i) {
      const int idx = tid + i*256;
      const int r = rA + i*32;
      gload16(Bsrc + (size_t)(n0b + r)*K + kbase + ((cA ^ (r & 7)) * 8), &Bs[idx*8]);
    }
    __syncthreads();
    #pragma unroll
    for (int kc = 0; kc < 2; ++kc) {
      const int kchunk = kc*4 + (lane >> 4);
      short8 a[4], b[2];
      #pragma unroll
      for (int mi = 0; mi < 4; ++mi) {
        const int m = wm + mi*16 + (lane & 15);
        a[mi] = *(const short8*)&As[m*64 + ((kchunk ^ (m & 7)) * 8)];
      }
      #pragma unroll
      for (int ni = 0; ni < 2; ++ni) {
        const int r = wn + ni*16 + (lane & 15);
        b[ni] = *(const short8*)&Bs[r*64 + ((kchunk ^ (r & 7)) * 8)];
      }
      #pragma unroll
      for (int mi = 0; mi < 4; ++mi)
        #pragma unroll
        for (int ni = 0; ni < 2; ++ni)
          acc[mi][ni] = __builtin_amdgcn_mfma_f32_16x16x32_bf16(a[mi], b[ni], acc[mi][ni], 0, 0, 0);
    }
  }

  const int mrow = (lane >> 4) * 4;
  #pragma unroll
  for (int mi = 0; mi < 4; ++mi) {
    const int mb = m0 + wm + mi*16 + mrow;
    if (mb >= 60000) continue;
    #pragma unroll
    for (int ni = 0; ni < 2; ++ni) {
      const int co = n0b + wn + ni*16 + (lane & 15);
      uint2 pk;
      pk.x = cvt_pk_bf16(acc[mi][ni][0], acc[mi][ni][1]);
      pk.y = cvt_pk_bf16(acc[mi][ni][2], acc[mi][ni][3]);
      *(uint2*)&Cb[(size_t)co*60000 + mb] = pk;
    }
  }
}

// ---------- bf16 MFMA GEMM, 128x256 tile, 512 thr (N=256: A read once) ----------
__global__ __launch_bounds__(512) void k_gemm2(const u16* __restrict__ Asrc,
    const u16* __restrict__ Bsrc, u16* __restrict__ Cb, int K) {
  const int m0 = blockIdx.x * 128;
  const int tid = threadIdx.x;
  const int lane = tid & 63, wid = tid >> 6;
  const int wm = (wid >> 2) * 64, wn = (wid & 3) * 64;

  __shared__ u16 As[128*64];
  __shared__ u16 Bs[256*64];

  f32x4 acc[4][4];
  #pragma unroll
  for (int mi = 0; mi < 4; ++mi)
    #pragma unroll
    for (int ni = 0; ni < 4; ++ni) acc[mi][ni] = (f32x4){0.f,0.f,0.f,0.f};

  const int rA = tid >> 3, cA = tid & 7;

  const int nkt = K >> 6;
  for (int kt = 0; kt < nkt; ++kt) {
    const int kbase = kt * 64;
    __syncthreads();
    #pragma unroll
    for (int i = 0; i < 2; ++i) {
      const int idx = tid + i*512;
      const int r = rA + i*64;
      int m = m0 + r; if (m > 59999) m = 59999;
      gload16(Asrc + (size_t)m*K + kbase + ((cA ^ (r & 7)) * 8), &As[idx*8]);
    }
    #pragma unroll
    for (int i = 0; i < 4; ++i) {
      const int idx = tid + i*512;
      const int r = rA + i*64;
      gload16(Bsrc + (size_t)r*K + kbase + ((cA ^ (r & 7)) * 8), &Bs[idx*8]);
    }
    __syncthreads();
    #pragma unroll
    for (int kc = 0; kc < 2; ++kc) {
      const int kchunk = kc*4 + (lane >> 4);
      short8 a[4], b[4];
      #pragma unroll
      for (int mi = 0; mi < 4; ++mi) {
        const int m = wm + mi*16 + (lane & 15);
        a[mi] = *(const short8*)&As[m*64 + ((kchunk ^ (m & 7)) * 8)];
      }
      #pragma unroll
      for (int ni = 0; ni < 4; ++ni) {
        const int r = wn + ni*16 + (lane & 15);
        b[ni] = *(const short8*)&Bs[r*64 + ((kchunk ^ (r & 7)) * 8)];
      }
      #pragma unroll
      for (int mi = 0; mi < 4; ++mi)
        #pragma unroll
        for (int ni = 0; ni < 4; ++ni)
          acc[mi][ni] = __builtin_amdgcn_mfma_f32_16x16x32_bf16(a[mi], b[ni], acc[mi][ni], 0, 0, 0);
    }
  }

  const int mrow = (lane >> 4) * 4;
  #pragma unroll
  for (int mi = 0; mi < 4; ++mi) {
    const int mb = m0 + wm + mi*16 + mrow;
    if (mb >= 60000) continue;
    #pragma unroll
    for (int ni = 0; ni < 4; ++ni) {
      const int co = wn + ni*16 + (lane & 15);
      uint2 pk;
      pk.x = cvt_pk_bf16(acc[mi][ni][0], acc[mi][ni][1]);
      pk.y = cvt_pk_bf16(acc[mi][ni][2], acc[mi][ni][3]);
      *(uint2*)&Cb[(size_t)co*60000 + mb] = pk;
    }
  }
}

// ---------- BN partial stats of windowed sum S (bf16 Z [co][60000]), per (c,n) ----------
__global__ __launch_bounds__(256) void k_bn_part_win(const u16* __restrict__ G,
    float* __restrict__ part, int cout) {
  const int c = blockIdx.x, n = blockIdx.y;
  const int tid = threadIdx.x;
  const u16* gb = G + (size_t)c*60000 + (size_t)n*7500;
  float s = 0.f, q = 0.f;
  for (int i = tid; i < 7500; i += 256) {
    const int ss = i / 25, w = i % 25;
    float S = 0.f;
    if (ss >= 8) {
      #pragma unroll
      for (int d = 0; d < 9; ++d) S += bf2f(gb[i - d*25]);
    } else {
      for (int tt = 0; tt <= ss; ++tt) S += bf2f(gb[tt*25 + w]);
    }
    s += S; q += S*S;
  }
  __shared__ float rs[256], rq[256];
  rs[tid] = s; rq[tid] = q;
  __syncthreads();
  for (int off = 128; off > 0; off >>= 1) {
    if (tid < off) { rs[tid] += rs[tid+off]; rq[tid] += rq[tid+off]; }
    __syncthreads();
  }
  if (tid == 0) {
    part[((size_t)c*8 + n)*2]     = rs[0];
    part[((size_t)c*8 + n)*2 + 1] = rq[0];
  }
}

// ---------- BN partial stats, plain (bf16 R [co][60000]) ----------
__global__ __launch_bounds__(256) void k_bn_part_plain(const u16* __restrict__ R,
    float* __restrict__ part, int cout) {
  const int c = blockIdx.x, n = blockIdx.y;
  const int tid = threadIdx.x;
  const u16* rb = R + (size_t)c*60000 + (size_t)n*7500;
  float s = 0.f, q = 0.f;
  for (int i = tid; i < 7500; i += 256) {
    const float val = bf2f(rb[i]);
    s += val; q += val*val;
  }
  __shared__ float rs[256], rq[256];
  rs[tid] = s; rq[tid] = q;
  __syncthreads();
  for (int off = 128; off > 0; off >>= 1) {
    if (tid < off) { rs[tid] += rs[tid+off]; rq[tid] += rq[tid+off]; }
    __syncthreads();
  }
  if (tid == 0) {
    part[((size_t)c*8 + n)*2]     = rs[0];
    part[((size_t)c*8 + n)*2 + 1] = rq[0];
  }
}

// ---------- fused BN-finalize + window-sum + BN + relu + residual ----------
__global__ __launch_bounds__(256) void k_apply2(const u16* __restrict__ G,
    const u16* __restrict__ Rb, const u16* Hres,
    const float* __restrict__ part, const float* __restrict__ g, const float* __restrict__ b,
    const float* __restrict__ rpart, const float* __restrict__ rg, const float* __restrict__ rbb,
    u16* Out, int cout, int mode) {
  const int bc = blockIdx.x;          // n*cout + c
  const int c = bc % cout, n = bc / cout;
  float s = 0.f, q = 0.f;
  #pragma unroll
  for (int i = 0; i < 8; ++i) {
    s += part[((size_t)c*8 + i)*2];
    q += part[((size_t)c*8 + i)*2 + 1];
  }
  const float mean = s / 60000.f;
  const float var  = q / 60000.f - mean*mean;
  const float sc = g[c] * rsqrtf(var + EPS);
  const float sh = b[c] - mean*sc;
  float rsc = 0.f, rsh = 0.f;
  if (mode == 1) {
    float s2 = 0.f, q2 = 0.f;
    #pragma unroll
    for (int i = 0; i < 8; ++i) {
      s2 += rpart[((size_t)c*8 + i)*2];
      q2 += rpart[((size_t)c*8 + i)*2 + 1];
    }
    const float m2 = s2 / 60000.f;
    const float v2 = q2 / 60000.f - m2*m2;
    rsc = rg[c] * rsqrtf(v2 + EPS);
    rsh = rbb[c] - m2*rsc;
  }
  const u16* gb = G + (size_t)c*60000 + (size_t)n*7500;
  const size_t rbase = (size_t)c*60000 + (size_t)n*7500;
  for (int i = threadIdx.x; i < 7500; i += 256) {
    const int ss = i / 25, w = i % 25;
    float S = 0.f;
    if (ss >= 8) {
      #pragma unroll
      for (int d = 0; d < 9; ++d) S += bf2f(gb[i - d*25]);
    } else {
      for (int tt = 0; tt <= ss; ++tt) S += bf2f(gb[tt*25 + w]);
    }
    const float h = fmaxf(S*sc + sh, 0.f);
    float o;
    if (mode == 0)      o = h;
    else if (mode == 1) o = fmaxf(h + (bf2f(Rb[rbase + i])*rsc + rsh), 0.f);
    else                o = fmaxf(h + bf2f(Hres[(size_t)bc*7500 + i]), 0.f);
    Out[(size_t)bc*7500 + i] = f2bf(o);
  }
}

// ---------- mean pool over joints ----------
__global__ void k_pool(const u16* __restrict__ H, float* __restrict__ HP) {
  const int idx = blockIdx.x*256 + threadIdx.x;
  if (idx >= 8*256*300) return;
  const u16* base = H + (size_t)idx * 25;
  float s = 0.f;
  #pragma unroll
  for (int v = 0; v < 25; ++v) s += bf2f(base[v]);
  HP[idx] = s * (1.f/25.f);
}

// ---------- classifier conv ----------
__global__ __launch_bounds__(256) void k_fout(const float* __restrict__ HP,
    const float* __restrict__ fW, const float* __restrict__ fb,
    float* __restrict__ out) {
  const int n = blockIdx.y;
  const int t0 = blockIdx.x * 32;
  const int tid = threadIdx.x;
  __shared__ float hp[256][32];
  for (int i = tid; i < 256*32; i += 256) {
    const int c = i / 32, tt = i % 32;
    const int t = t0 + tt;
    hp[c][tt] = (t < 300) ? HP[((size_t)n*256 + c)*300 + t] : 0.f;
  }
  __syncthreads();
  for (int e = tid; e < 60*32; e += 256) {
    const int o = e / 32, tt = e % 32;
    const int t = t0 + tt;
    if (t >= 300) continue;
    float acc = fb[o];
    for (int c = 0; c < 256; ++c) acc += hp[c][tt] * fW[o*256 + c];
    out[((size_t)n*60 + o)*300 + t] = acc;
  }
}

extern "C" void kernel_launch(void* const* d_in, const int* in_sizes, int n_in,
                              void* d_out, int out_size, void* d_ws, size_t ws_size,
                              hipStream_t stream) {
  (void)in_sizes; (void)n_in; (void)out_size; (void)ws_size;
  const float* x     = (const float*)d_in[0];
  const float* A     = (const float*)d_in[1];
  const float* bng   = (const float*)d_in[2];
  const float* bnb   = (const float*)d_in[3];
  const float* finW  = (const float*)d_in[4];
  const float* finb  = (const float*)d_in[5];
  const float* imp0  = (const float*)d_in[6];
  const float* imp1  = (const float*)d_in[7];
  const float* imp2  = (const float*)d_in[8];
  const float* imp3  = (const float*)d_in[9];
  const float* W0    = (const float*)d_in[10];
  const float* g0    = (const float*)d_in[11];
  const float* b0    = (const float*)d_in[12];
  const float* W1    = (const float*)d_in[13];
  const float* g1    = (const float*)d_in[14];
  const float* b1    = (const float*)d_in[15];
  const float* Wr1   = (const float*)d_in[16];
  const float* gr1   = (const float*)d_in[17];
  const float* br1   = (const float*)d_in[18];
  const float* W2    = (const float*)d_in[19];
  const float* g2    = (const float*)d_in[20];
  const float* b2    = (const float*)d_in[21];
  const float* Wr2   = (const float*)d_in[22];
  const float* gr2   = (const float*)d_in[23];
  const float* br2   = (const float*)d_in[24];
  const float* W3    = (const float*)d_in[25];
  const float* g3    = (const float*)d_in[26];
  const float* b3    = (const float*)d_in[27];
  const float* foutW = (const float*)d_in[28];
  const float* foutb = (const float*)d_in[29];
  float* out = (float*)d_out;

  char* base = (char*)d_ws;
  u16*   Z    = (u16*)base;                        // bf16 [co][60000] (<=30.72 MB)
  u16*   Hmk  = (u16*)base;                        // overlay (dead before Z written)
  float* HP   = (float*)(base + 40000000);         // in unused Z-region slack
  float* PART = (float*)(base + 45000000);
  float* RPART= (float*)(base + 45100000);
  u16*   XA   = (u16*)(base + 61440000);           // bf16 [60000][K], up to 92.16 MB
  u16*   Rb   = (u16*)(base + 107520000);          // bf16 [co][60000] (layers 1,2 only)
  u16*   Hct  = (u16*)(base + 153600000);          // bf16 [n][c][t][v], 30.72 MB
  u16*   HPAD = (u16*)(base + 184320000);          // 64B zero pad (xa_mfma overhang)
  u16*   ATb  = (u16*)(base + 185000000);          // bf16 [4][3][32][32]
  u16*   WT   = (u16*)(base + 186777600);
  float* Ap   = (float*)(base + 187523072);
  float* ST   = Ap + 7500;
  float* ISC = ST, *ISH = ST + 80;

  u16* W0t  = WT;            // 64 x 192
  u16* W1t  = WT + 12288;    // 128 x 192
  u16* Wr1t = WT + 36864;    // 128 x 64
  u16* W2t  = WT + 45056;    // 256 x 384
  u16* Wr2t = WT + 143360;   // 256 x 128
  u16* W3t  = WT + 176128;   // 256 x 768

  // ---- prep (single kernel) ----
  k_prep_all<<<1534, 256, 0, stream>>>(A, imp0, imp1, imp2, imp3,
      W0, W1, Wr1, W2, Wr2, W3, Ap, W0t, W1t, Wr1t, W2t, Wr2t, W3t, ATb, HPAD);

  k_bn_in_stats<<<75, 256, 0, stream>>>(x, bng, bnb, ISC, ISH);
  k_fin<<<dim3(30, 8), 256, 0, stream>>>(x, ISC, ISH, finW, finb, Hct);

  const int lds64  = (64*27  + 2100) * 4;
  const int lds128 = (128*27 + 2100) * 4;
  const int MT = 469;   // ceil(60000/128)

  // ---- layer 0: 64 -> 64 (MFMA xa) ----
  k_xa_mfma<<<dim3(75, 8), 256, 0, stream>>>(Hct, ATb, XA, 64, 192);
  k_gemm<<<dim3(1, MT), 256, 0, stream>>>(XA, W0t, Z, 192);
  k_bn_part_win<<<dim3(64, 8), 256, 0, stream>>>(Z, PART, 64);
  k_apply2<<<8*64, 256, 0, stream>>>(Z, nullptr, nullptr, PART, g0, b0,
      nullptr, nullptr, nullptr, Hct, 64, 0);

  // ---- layer 1: 64 -> 128 (VALU xa, makes Hmk) ----
  k_xa3<<<dim3(150, 8), 256, lds64, stream>>>(Hct, Ap + 1875, XA, Hmk, 64, 6);
  k_gemm<<<dim3(2, MT), 256, 0, stream>>>(Hmk, Wr1t, Rb, 64);
  k_bn_part_plain<<<dim3(128, 8), 256, 0, stream>>>(Rb, RPART, 128);
  k_gemm<<<dim3(2, MT), 256, 0, stream>>>(XA, W1t, Z, 192);
  k_bn_part_win<<<dim3(128, 8), 256, 0, stream>>>(Z, PART, 128);
  k_apply2<<<8*128, 256, 0, stream>>>(Z, Rb, nullptr, PART, g1, b1,
      RPART, gr1, br1, Hct, 128, 1);

  // ---- layer 2: 128 -> 256 (VALU xa, makes Hmk; N=256 gemms) ----
  k_xa3<<<dim3(150, 8), 256, lds128, stream>>>(Hct, Ap + 3750, XA, Hmk, 128, 7);
  k_gemm2<<<MT, 512, 0, stream>>>(Hmk, Wr2t, Rb, 128);
  k_bn_part_plain<<<dim3(256, 8), 256, 0, stream>>>(Rb, RPART, 256);
  k_gemm2<<<MT, 512, 0, stream>>>(XA, W2t, Z, 384);
  k_bn_part_win<<<dim3(256, 8), 256, 0, stream>>>(Z, PART, 256);
  k_apply2<<<8*256, 256, 0, stream>>>(Z, Rb, nullptr, PART, g2, b2,
      RPART, gr2, br2, Hct, 256, 1);

  // ---- layer 3: 256 -> 256, identity residual (MFMA xa, N=256 gemm) ----
  k_xa_mfma<<<dim3(75, 8), 256, 0, stream>>>(Hct, ATb + 3*3072, XA, 256, 768);
  k_gemm2<<<MT, 512, 0, stream>>>(XA, W3t, Z, 768);
  k_bn_part_win<<<dim3(256, 8), 256, 0, stream>>>(Z, PART, 256);
  k_apply2<<<8*256, 256, 0, stream>>>(Z, nullptr, Hct, PART, g3, b3,
      nullptr, nullptr, nullptr, Hct, 256, 2);

  // ---- head ----
  k_pool<<<2400, 256, 0, stream>>>(Hct, HP);
  k_fout<<<dim3(10, 8), 256, 0, stream>>>(HP, foutW, foutb, out);
}

// Round 8
// 473.673 us; speedup vs baseline: 1.6216x; 1.0149x over previous
//
#include <hip/hip_runtime.h>

#define EPS 1e-5f
typedef unsigned short u16;
typedef __attribute__((ext_vector_type(8))) short short8;
typedef __attribute__((ext_vector_type(4))) float f32x4;

__device__ __forceinline__ float bf2f(u16 u) {
  union { unsigned int i; float f; } c; c.i = ((unsigned int)u) << 16; return c.f;
}
__device__ __forceinline__ u16 f2bf(float f) {
  union { float f; unsigned int i; } c; c.f = f;
  unsigned int u = c.i;
  u += 0x7fffu + ((u >> 16) & 1u);   // round-to-nearest-even
  return (u16)(u >> 16);
}
__device__ __forceinline__ unsigned int cvt_pk_bf16(float lo, float hi) {
  unsigned int r;
  asm("v_cvt_pk_bf16_f32 %0, %1, %2" : "=v"(r) : "v"(lo), "v"(hi));
  return r;
}
// unaligned-safe 16B load (H rows are 50B-strided)
__device__ __forceinline__ short8 load8u(const u16* p) {
  short8 v; __builtin_memcpy(&v, p, 16); return v;
}
// async global->LDS, 16B per lane; dest = wave-uniform base + lane*16 (linear)
__device__ __forceinline__ void gload16(const u16* g, u16* l) {
  __builtin_amdgcn_global_load_lds(
      (__attribute__((address_space(1))) void*)(void*)g,
      (__attribute__((address_space(3))) void*)l, 16, 0, 0);
}

// ---------- merged prep: 6 weight transposes, ATb, Hct end-pad ----------
__device__ __forceinline__ void prep_w_elem(const float* W, u16* Wt,
    int cin, int cout, int P, int idx) {
  const int K = P*cin;
  const int co = idx / K, k = idx % K;
  const int p = k / cin, ci = k % cin;
  Wt[idx] = f2bf(W[((size_t)(p*cout + co))*cin + ci]);
}

__global__ __launch_bounds__(256) void k_prep_all(
    const float* __restrict__ A,
    const float* __restrict__ i0, const float* __restrict__ i1,
    const float* __restrict__ i2, const float* __restrict__ i3,
    const float* __restrict__ W0, const float* __restrict__ W1,
    const float* __restrict__ Wr1, const float* __restrict__ W2,
    const float* __restrict__ Wr2, const float* __restrict__ W3,
    u16* W0t, u16* W1t, u16* Wr1t, u16* W2t,
    u16* Wr2t, u16* W3t, u16* ATb, u16* hpad) {
  int idx = blockIdx.x*256 + threadIdx.x;
  if (idx < 12288) { prep_w_elem(W0,  W0t,  64,  64,  3, idx); return; }
  idx -= 12288;
  if (idx < 24576) { prep_w_elem(W1,  W1t,  64,  128, 3, idx); return; }
  idx -= 24576;
  if (idx < 8192)  { prep_w_elem(Wr1, Wr1t, 64,  128, 1, idx); return; }
  idx -= 8192;
  if (idx < 98304) { prep_w_elem(W2,  W2t,  128, 256, 3, idx); return; }
  idx -= 98304;
  if (idx < 32768) { prep_w_elem(Wr2, Wr2t, 128, 256, 1, idx); return; }
  idx -= 32768;
  if (idx < 196608){ prep_w_elem(W3,  W3t,  256, 256, 3, idx); return; }
  idx -= 196608;
  if (idx < 12288) {                     // ATb[l][p][w(32)][v(32)] = bf16(A'[p][v][w]), zero-padded
    const int l = idx / 3072, r = idx % 3072;
    const int p = r / 1024, wv = r % 1024;
    const int w = wv >> 5, v = wv & 31;
    float val = 0.f;
    if (w < 25 && v < 25) {
      const float* imp = (l==0)?i0:(l==1)?i1:(l==2)?i2:i3;
      val = A[(p*25 + v)*25 + w] * imp[v*25 + w];
    }
    ATb[idx] = f2bf(val);
    return;
  }
  idx -= 12288;
  if (idx < 32) hpad[idx] = 0;           // safe overhang for xa_mfma A-frags
}

// ---------- input BN stats: per j = v*3+c over (n,t) ----------
__global__ __launch_bounds__(256) void k_bn_in_stats(const float* __restrict__ x,
    const float* __restrict__ g, const float* __restrict__ b,
    float* __restrict__ iscale, float* __restrict__ ishift) {
  const int j = blockIdx.x;            // 0..74
  const int c = j % 3, v = j / 3;
  const int tid = threadIdx.x;
  float s = 0.f, q = 0.f;
  for (int i = tid; i < 2400; i += 256) {
    const int n = i / 300, t = i % 300;
    const float val = x[(((size_t)n*3 + c)*300 + t)*25 + v];
    s += val; q += val*val;
  }
  __shared__ float rs[256], rq[256];
  rs[tid] = s; rq[tid] = q;
  __syncthreads();
  for (int off = 128; off > 0; off >>= 1) {
    if (tid < off) { rs[tid] += rs[tid+off]; rq[tid] += rq[tid+off]; }
    __syncthreads();
  }
  if (tid == 0) {
    const float mean = rs[0] / 2400.f;
    const float var  = rq[0] / 2400.f - mean*mean;
    const float sc = g[j] * rsqrtf(var + EPS);
    iscale[j] = sc;
    ishift[j] = b[j] - mean*sc;
  }
}

// ---------- fused input-BN apply + fin (3 -> 64), writes bf16 H_ct ----------
__global__ __launch_bounds__(256) void k_fin(const float* __restrict__ x,
    const float* __restrict__ iscale, const float* __restrict__ ishift,
    const float* __restrict__ fW, const float* __restrict__ fb,
    u16* __restrict__ H) {
  const int n = blockIdx.y;
  const int t0 = blockIdx.x * 10;
  const int tid = threadIdx.x;
  __shared__ float xn[3][250];
  __shared__ float wsh[64][3];
  __shared__ float bsh[64];
  if (tid < 192) wsh[tid/3][tid%3] = fW[tid];
  if (tid < 64)  bsh[tid] = fb[tid];
  for (int i = tid; i < 750; i += 256) {
    const int c = i / 250, pos = i % 250;
    const int t = t0 + pos/25, v = pos%25;
    const int j = v*3 + c;
    xn[c][pos] = x[(((size_t)n*3 + c)*300 + t)*25 + v] * iscale[j] + ishift[j];
  }
  __syncthreads();
  for (int e = tid; e < 64*250; e += 256) {
    const int o = e / 250, pos = e % 250;
    float acc = bsh[o]
              + xn[0][pos]*wsh[o][0] + xn[1][pos]*wsh[o][1] + xn[2][pos]*wsh[o][2];
    const int t = t0 + pos/25, v = pos%25;
    H[(((size_t)n*64 + o)*300 + t)*25 + v] = f2bf(acc);
  }
}

// ---------- Hmk transpose: Hmk[(n*7500+m)][ci] = H[n][ci][m] ----------
__global__ __launch_bounds__(256) void k_hmk(const u16* __restrict__ H,
    u16* __restrict__ Hmk, int cin) {
  const int m0  = blockIdx.x * 64;
  const int ci0 = blockIdx.y * 32;
  const int n   = blockIdx.z;
  __shared__ u16 tile[32][72];
  const int tid = threadIdx.x;
  {
    const int ci = tid >> 3, chunk = tid & 7;
    const int m = m0 + chunk * 8;
    const u16* src = &H[(size_t)(n*cin + ci0 + ci)*7500];
    short8 v;
    if (m + 7 < 7500) {
      v = load8u(&src[m]);
    } else {
      #pragma unroll
      for (int j = 0; j < 8; ++j)
        ((u16*)&v)[j] = (m + j < 7500) ? src[m + j] : (u16)0;
    }
    *(short8*)&tile[ci][chunk*8] = v;
  }
  __syncthreads();
  const int mr = tid >> 2, cq = (tid & 3) * 8;
  const int m = m0 + mr;
  if (m < 7500) {
    short8 v;
    #pragma unroll
    for (int j = 0; j < 8; ++j) ((u16*)&v)[j] = tile[cq + j][mr];
    *(short8*)&Hmk[((size_t)n*7500 + m)*cin + ci0 + cq] = v;
  }
}

// ---------- xa via MFMA: XA[(n,t,w)][p*cin+ci] = sum_v H[ci][t][v] * AT[p][w][v] ----------
__global__ __launch_bounds__(256) void k_xa_mfma(const u16* __restrict__ H,
    const u16* __restrict__ ATl, u16* __restrict__ XA, int cin, int K) {
  const int lane = threadIdx.x & 63, wid = threadIdx.x >> 6;
  const int t = blockIdx.x * 4 + wid;      // 4 waves = 4 timesteps per block
  const int n = blockIdx.y;
  const int lrow = lane & 15, lchunk = lane >> 4;
  short8 bf[3][2];
  #pragma unroll
  for (int p = 0; p < 3; ++p)
    #pragma unroll
    for (int wt = 0; wt < 2; ++wt)
      bf[p][wt] = *(const short8*)&ATl[(p*32 + wt*16 + lrow)*32 + lchunk*8];
  const int ntile = cin >> 4;
  const size_t mrow0 = ((size_t)n*300 + t)*25;
  const int ciq = lchunk*4;
  for (int citile = 0; citile < ntile; ++citile) {
    const int ci = citile*16 + lrow;
    const short8 af = load8u(&H[((size_t)(n*cin + ci)*300 + t)*25 + lchunk*8]);
    #pragma unroll
    for (int p = 0; p < 3; ++p) {
      #pragma unroll
      for (int wt = 0; wt < 2; ++wt) {
        f32x4 acc = (f32x4){0.f, 0.f, 0.f, 0.f};
        acc = __builtin_amdgcn_mfma_f32_16x16x32_bf16(af, bf[p][wt], acc, 0, 0, 0);
        const int w = wt*16 + lrow;
        if (w < 25) {
          uint2 pk;
          pk.x = cvt_pk_bf16(acc[0], acc[1]);
          pk.y = cvt_pk_bf16(acc[2], acc[3]);
          *(uint2*)&XA[(mrow0 + w)*K + p*cin + citile*16 + ciq] = pk;
        }
      }
    }
  }
}

// ---------- bf16 MFMA GEMM, 128x64 tile (N=64/128) ----------
__global__ __launch_bounds__(256) void k_gemm(const u16* __restrict__ Asrc,
    const u16* __restrict__ Bsrc, u16* __restrict__ Cb, int K) {
  const int n0b = blockIdx.x * 64;
  const int m0  = blockIdx.y * 128;
  const int tid = threadIdx.x;
  const int lane = tid & 63, wid = tid >> 6;
  const int wm = (wid & 1) * 64, wn = (wid >> 1) * 32;

  __shared__ u16 As[128*64];
  __shared__ u16 Bs[64*64];

  f32x4 acc[4][2];
  #pragma unroll
  for (int mi = 0; mi < 4; ++mi)
    #pragma unroll
    for (int ni = 0; ni < 2; ++ni) acc[mi][ni] = (f32x4){0.f,0.f,0.f,0.f};

  const int rA = tid >> 3, cA = tid & 7;

  const int nkt = K >> 6;
  for (int kt = 0; kt < nkt; ++kt) {
    const int kbase = kt * 64;
    __syncthreads();
    #pragma unroll
    for (int i = 0; i < 4; ++i) {
      const int idx = tid + i*256;
      const int r = rA + i*32;
      int m = m0 + r; if (m > 59999) m = 59999;
      gload16(Asrc + (size_t)m*K + kbase + ((cA ^ (r & 7)) * 8), &As[idx*8]);
    }
    #pragma unroll
    for (int i = 0; i < 2; ++i) {
      const int idx = tid + i*256;
      const int r = rA + i*32;
      gload16(Bsrc + (size_t)(n0b + r)*K + kbase + ((cA ^ (r & 7)) * 8), &Bs[idx*8]);
    }
    __syncthreads();
    #pragma unroll
    for (int kc = 0; kc < 2; ++kc) {
      const int kchunk = kc*4 + (lane >> 4);
      short8 a[4], b[2];
      #pragma unroll
      for (int mi = 0; mi < 4; ++mi) {
        const int m = wm + mi*16 + (lane & 15);
        a[mi] = *(const short8*)&As[m*64 + ((kchunk ^ (m & 7)) * 8)];
      }
      #pragma unroll
      for (int ni = 0; ni < 2; ++ni) {
        const int r = wn + ni*16 + (lane & 15);
        b[ni] = *(const short8*)&Bs[r*64 + ((kchunk ^ (r & 7)) * 8)];
      }
      #pragma unroll
      for (int mi = 0; mi < 4; ++mi)
        #pragma unroll
        for (int ni = 0; ni < 2; ++ni)
          acc[mi][ni] = __builtin_amdgcn_mfma_f32_16x16x32_bf16(a[mi], b[ni], acc[mi][ni], 0, 0, 0);
    }
  }

  const int mrow = (lane >> 4) * 4;
  #pragma unroll
  for (int mi = 0; mi < 4; ++mi) {
    const int mb = m0 + wm + mi*16 + mrow;
    if (mb >= 60000) continue;
    #pragma unroll
    for (int ni = 0; ni < 2; ++ni) {
      const int co = n0b + wn + ni*16 + (lane & 15);
      uint2 pk;
      pk.x = cvt_pk_bf16(acc[mi][ni][0], acc[mi][ni][1]);
      pk.y = cvt_pk_bf16(acc[mi][ni][2], acc[mi][ni][3]);
      *(uint2*)&Cb[(size_t)co*60000 + mb] = pk;
    }
  }
}

// ---------- bf16 MFMA GEMM, 128x256 tile, 512 thr (N=256: A read once) ----------
__global__ __launch_bounds__(512) void k_gemm2(const u16* __restrict__ Asrc,
    const u16* __restrict__ Bsrc, u16* __restrict__ Cb, int K) {
  const int m0 = blockIdx.x * 128;
  const int tid = threadIdx.x;
  const int lane = tid & 63, wid = tid >> 6;
  const int wm = (wid >> 2) * 64, wn = (wid & 3) * 64;

  __shared__ u16 As[128*64];
  __shared__ u16 Bs[256*64];

  f32x4 acc[4][4];
  #pragma unroll
  for (int mi = 0; mi < 4; ++mi)
    #pragma unroll
    for (int ni = 0; ni < 4; ++ni) acc[mi][ni] = (f32x4){0.f,0.f,0.f,0.f};

  const int rA = tid >> 3, cA = tid & 7;

  const int nkt = K >> 6;
  for (int kt = 0; kt < nkt; ++kt) {
    const int kbase = kt * 64;
    __syncthreads();
    #pragma unroll
    for (int i = 0; i < 2; ++i) {
      const int idx = tid + i*512;
      const int r = rA + i*64;
      int m = m0 + r; if (m > 59999) m = 59999;
      gload16(Asrc + (size_t)m*K + kbase + ((cA ^ (r & 7)) * 8), &As[idx*8]);
    }
    #pragma unroll
    for (int i = 0; i < 4; ++i) {
      const int idx = tid + i*512;
      const int r = rA + i*64;
      gload16(Bsrc + (size_t)r*K + kbase + ((cA ^ (r & 7)) * 8), &Bs[idx*8]);
    }
    __syncthreads();
    #pragma unroll
    for (int kc = 0; kc < 2; ++kc) {
      const int kchunk = kc*4 + (lane >> 4);
      short8 a[4], b[4];
      #pragma unroll
      for (int mi = 0; mi < 4; ++mi) {
        const int m = wm + mi*16 + (lane & 15);
        a[mi] = *(const short8*)&As[m*64 + ((kchunk ^ (m & 7)) * 8)];
      }
      #pragma unroll
      for (int ni = 0; ni < 4; ++ni) {
        const int r = wn + ni*16 + (lane & 15);
        b[ni] = *(const short8*)&Bs[r*64 + ((kchunk ^ (r & 7)) * 8)];
      }
      #pragma unroll
      for (int mi = 0; mi < 4; ++mi)
        #pragma unroll
        for (int ni = 0; ni < 4; ++ni)
          acc[mi][ni] = __builtin_amdgcn_mfma_f32_16x16x32_bf16(a[mi], b[ni], acc[mi][ni], 0, 0, 0);
    }
  }

  const int mrow = (lane >> 4) * 4;
  #pragma unroll
  for (int mi = 0; mi < 4; ++mi) {
    const int mb = m0 + wm + mi*16 + mrow;
    if (mb >= 60000) continue;
    #pragma unroll
    for (int ni = 0; ni < 4; ++ni) {
      const int co = wn + ni*16 + (lane & 15);
      uint2 pk;
      pk.x = cvt_pk_bf16(acc[mi][ni][0], acc[mi][ni][1]);
      pk.y = cvt_pk_bf16(acc[mi][ni][2], acc[mi][ni][3]);
      *(uint2*)&Cb[(size_t)co*60000 + mb] = pk;
    }
  }
}

// ---------- BN partial stats of windowed sum S (bf16 Z [co][60000]), per (c,n) ----------
__global__ __launch_bounds__(256) void k_bn_part_win(const u16* __restrict__ G,
    float* __restrict__ part, int cout) {
  const int c = blockIdx.x, n = blockIdx.y;
  const int tid = threadIdx.x;
  const u16* gb = G + (size_t)c*60000 + (size_t)n*7500;
  float s = 0.f, q = 0.f;
  for (int i = tid; i < 7500; i += 256) {
    const int ss = i / 25, w = i % 25;
    float S = 0.f;
    if (ss >= 8) {
      #pragma unroll
      for (int d = 0; d < 9; ++d) S += bf2f(gb[i - d*25]);
    } else {
      for (int tt = 0; tt <= ss; ++tt) S += bf2f(gb[tt*25 + w]);
    }
    s += S; q += S*S;
  }
  __shared__ float rs[256], rq[256];
  rs[tid] = s; rq[tid] = q;
  __syncthreads();
  for (int off = 128; off > 0; off >>= 1) {
    if (tid < off) { rs[tid] += rs[tid+off]; rq[tid] += rq[tid+off]; }
    __syncthreads();
  }
  if (tid == 0) {
    part[((size_t)c*8 + n)*2]     = rs[0];
    part[((size_t)c*8 + n)*2 + 1] = rq[0];
  }
}

// ---------- BN partial stats, plain (bf16 R [co][60000]) ----------
__global__ __launch_bounds__(256) void k_bn_part_plain(const u16* __restrict__ R,
    float* __restrict__ part, int cout) {
  const int c = blockIdx.x, n = blockIdx.y;
  const int tid = threadIdx.x;
  const u16* rb = R + (size_t)c*60000 + (size_t)n*7500;
  float s = 0.f, q = 0.f;
  for (int i = tid; i < 7500; i += 256) {
    const float val = bf2f(rb[i]);
    s += val; q += val*val;
  }
  __shared__ float rs[256], rq[256];
  rs[tid] = s; rq[tid] = q;
  __syncthreads();
  for (int off = 128; off > 0; off >>= 1) {
    if (tid < off) { rs[tid] += rs[tid+off]; rq[tid] += rq[tid+off]; }
    __syncthreads();
  }
  if (tid == 0) {
    part[((size_t)c*8 + n)*2]     = rs[0];
    part[((size_t)c*8 + n)*2 + 1] = rq[0];
  }
}

// ---------- fused BN-finalize + window-sum + BN + relu + residual ----------
__global__ __launch_bounds__(256) void k_apply2(const u16* __restrict__ G,
    const u16* __restrict__ Rb, const u16* Hres,
    const float* __restrict__ part, const float* __restrict__ g, const float* __restrict__ b,
    const float* __restrict__ rpart, const float* __restrict__ rg, const float* __restrict__ rbb,
    u16* Out, int cout, int mode) {
  const int bc = blockIdx.x;          // n*cout + c
  const int c = bc % cout, n = bc / cout;
  float s = 0.f, q = 0.f;
  #pragma unroll
  for (int i = 0; i < 8; ++i) {
    s += part[((size_t)c*8 + i)*2];
    q += part[((size_t)c*8 + i)*2 + 1];
  }
  const float mean = s / 60000.f;
  const float var  = q / 60000.f - mean*mean;
  const float sc = g[c] * rsqrtf(var + EPS);
  const float sh = b[c] - mean*sc;
  float rsc = 0.f, rsh = 0.f;
  if (mode == 1) {
    float s2 = 0.f, q2 = 0.f;
    #pragma unroll
    for (int i = 0; i < 8; ++i) {
      s2 += rpart[((size_t)c*8 + i)*2];
      q2 += rpart[((size_t)c*8 + i)*2 + 1];
    }
    const float m2 = s2 / 60000.f;
    const float v2 = q2 / 60000.f - m2*m2;
    rsc = rg[c] * rsqrtf(v2 + EPS);
    rsh = rbb[c] - m2*rsc;
  }
  const u16* gb = G + (size_t)c*60000 + (size_t)n*7500;
  const size_t rbase = (size_t)c*60000 + (size_t)n*7500;
  for (int i = threadIdx.x; i < 7500; i += 256) {
    const int ss = i / 25, w = i % 25;
    float S = 0.f;
    if (ss >= 8) {
      #pragma unroll
      for (int d = 0; d < 9; ++d) S += bf2f(gb[i - d*25]);
    } else {
      for (int tt = 0; tt <= ss; ++tt) S += bf2f(gb[tt*25 + w]);
    }
    const float h = fmaxf(S*sc + sh, 0.f);
    float o;
    if (mode == 0)      o = h;
    else if (mode == 1) o = fmaxf(h + (bf2f(Rb[rbase + i])*rsc + rsh), 0.f);
    else                o = fmaxf(h + bf2f(Hres[(size_t)bc*7500 + i]), 0.f);
    Out[(size_t)bc*7500 + i] = f2bf(o);
  }
}

// ---------- mean pool over joints ----------
__global__ void k_pool(const u16* __restrict__ H, float* __restrict__ HP) {
  const int idx = blockIdx.x*256 + threadIdx.x;
  if (idx >= 8*256*300) return;
  const u16* base = H + (size_t)idx * 25;
  float s = 0.f;
  #pragma unroll
  for (int v = 0; v < 25; ++v) s += bf2f(base[v]);
  HP[idx] = s * (1.f/25.f);
}

// ---------- classifier conv ----------
__global__ __launch_bounds__(256) void k_fout(const float* __restrict__ HP,
    const float* __restrict__ fW, const float* __restrict__ fb,
    float* __restrict__ out) {
  const int n = blockIdx.y;
  const int t0 = blockIdx.x * 32;
  const int tid = threadIdx.x;
  __shared__ float hp[256][32];
  for (int i = tid; i < 256*32; i += 256) {
    const int c = i / 32, tt = i % 32;
    const int t = t0 + tt;
    hp[c][tt] = (t < 300) ? HP[((size_t)n*256 + c)*300 + t] : 0.f;
  }
  __syncthreads();
  for (int e = tid; e < 60*32; e += 256) {
    const int o = e / 32, tt = e % 32;
    const int t = t0 + tt;
    if (t >= 300) continue;
    float acc = fb[o];
    for (int c = 0; c < 256; ++c) acc += hp[c][tt] * fW[o*256 + c];
    out[((size_t)n*60 + o)*300 + t] = acc;
  }
}

extern "C" void kernel_launch(void* const* d_in, const int* in_sizes, int n_in,
                              void* d_out, int out_size, void* d_ws, size_t ws_size,
                              hipStream_t stream) {
  (void)in_sizes; (void)n_in; (void)out_size; (void)ws_size;
  const float* x     = (const float*)d_in[0];
  const float* A     = (const float*)d_in[1];
  const float* bng   = (const float*)d_in[2];
  const float* bnb   = (const float*)d_in[3];
  const float* finW  = (const float*)d_in[4];
  const float* finb  = (const float*)d_in[5];
  const float* imp0  = (const float*)d_in[6];
  const float* imp1  = (const float*)d_in[7];
  const float* imp2  = (const float*)d_in[8];
  const float* imp3  = (const float*)d_in[9];
  const float* W0    = (const float*)d_in[10];
  const float* g0    = (const float*)d_in[11];
  const float* b0    = (const float*)d_in[12];
  const float* W1    = (const float*)d_in[13];
  const float* g1    = (const float*)d_in[14];
  const float* b1    = (const float*)d_in[15];
  const float* Wr1   = (const float*)d_in[16];
  const float* gr1   = (const float*)d_in[17];
  const float* br1   = (const float*)d_in[18];
  const float* W2    = (const float*)d_in[19];
  const float* g2    = (const float*)d_in[20];
  const float* b2    = (const float*)d_in[21];
  const float* Wr2   = (const float*)d_in[22];
  const float* gr2   = (const float*)d_in[23];
  const float* br2   = (const float*)d_in[24];
  const float* W3    = (const float*)d_in[25];
  const float* g3    = (const float*)d_in[26];
  const float* b3    = (const float*)d_in[27];
  const float* foutW = (const float*)d_in[28];
  const float* foutb = (const float*)d_in[29];
  float* out = (float*)d_out;

  char* base = (char*)d_ws;
  u16*   Z    = (u16*)base;                        // bf16 [co][60000] (<=30.72 MB)
  u16*   Hmk  = (u16*)base;                        // overlay (dead before Z written)
  float* HP   = (float*)(base + 40000000);         // in unused Z-region slack
  float* PART = (float*)(base + 45000000);
  float* RPART= (float*)(base + 45100000);
  u16*   XA   = (u16*)(base + 61440000);           // bf16 [60000][K], up to 92.16 MB
  u16*   Rb   = (u16*)(base + 107520000);          // bf16 [co][60000] (layers 1,2 only)
  u16*   Hct  = (u16*)(base + 153600000);          // bf16 [n][c][t][v], 30.72 MB
  u16*   HPAD = (u16*)(base + 184320000);          // 64B zero pad (xa_mfma overhang)
  u16*   ATb  = (u16*)(base + 185000000);          // bf16 [4][3][32][32]
  u16*   WT   = (u16*)(base + 186777600);
  float* ST   = (float*)(base + 188000000);
  float* ISC = ST, *ISH = ST + 80;

  u16* W0t  = WT;            // 64 x 192
  u16* W1t  = WT + 12288;    // 128 x 192
  u16* Wr1t = WT + 36864;    // 128 x 64
  u16* W2t  = WT + 45056;    // 256 x 384
  u16* Wr2t = WT + 143360;   // 256 x 128
  u16* W3t  = WT + 176128;   // 256 x 768

  // ---- prep (single kernel) ----
  k_prep_all<<<1505, 256, 0, stream>>>(A, imp0, imp1, imp2, imp3,
      W0, W1, Wr1, W2, Wr2, W3, W0t, W1t, Wr1t, W2t, Wr2t, W3t, ATb, HPAD);

  k_bn_in_stats<<<75, 256, 0, stream>>>(x, bng, bnb, ISC, ISH);
  k_fin<<<dim3(30, 8), 256, 0, stream>>>(x, ISC, ISH, finW, finb, Hct);

  const int MT = 469;   // ceil(60000/128)

  // ---- layer 0: 64 -> 64 (MFMA xa) ----
  k_xa_mfma<<<dim3(75, 8), 256, 0, stream>>>(Hct, ATb, XA, 64, 192);
  k_gemm<<<dim3(1, MT), 256, 0, stream>>>(XA, W0t, Z, 192);
  k_bn_part_win<<<dim3(64, 8), 256, 0, stream>>>(Z, PART, 64);
  k_apply2<<<8*64, 256, 0, stream>>>(Z, nullptr, nullptr, PART, g0, b0,
      nullptr, nullptr, nullptr, Hct, 64, 0);

  // ---- layer 1: 64 -> 128 (MFMA xa + hmk transpose) ----
  k_hmk<<<dim3(118, 2, 8), 256, 0, stream>>>(Hct, Hmk, 64);
  k_xa_mfma<<<dim3(75, 8), 256, 0, stream>>>(Hct, ATb + 1*3072, XA, 64, 192);
  k_gemm<<<dim3(2, MT), 256, 0, stream>>>(Hmk, Wr1t, Rb, 64);
  k_bn_part_plain<<<dim3(128, 8), 256, 0, stream>>>(Rb, RPART, 128);
  k_gemm<<<dim3(2, MT), 256, 0, stream>>>(XA, W1t, Z, 192);
  k_bn_part_win<<<dim3(128, 8), 256, 0, stream>>>(Z, PART, 128);
  k_apply2<<<8*128, 256, 0, stream>>>(Z, Rb, nullptr, PART, g1, b1,
      RPART, gr1, br1, Hct, 128, 1);

  // ---- layer 2: 128 -> 256 (MFMA xa + hmk transpose; N=256 gemms) ----
  k_hmk<<<dim3(118, 4, 8), 256, 0, stream>>>(Hct, Hmk, 128);
  k_xa_mfma<<<dim3(75, 8), 256, 0, stream>>>(Hct, ATb + 2*3072, XA, 128, 384);
  k_gemm2<<<MT, 512, 0, stream>>>(Hmk, Wr2t, Rb, 128);
  k_bn_part_plain<<<dim3(256, 8), 256, 0, stream>>>(Rb, RPART, 256);
  k_gemm2<<<MT, 512, 0, stream>>>(XA, W2t, Z, 384);
  k_bn_part_win<<<dim3(256, 8), 256, 0, stream>>>(Z, PART, 256);
  k_apply2<<<8*256, 256, 0, stream>>>(Z, Rb, nullptr, PART, g2, b2,
      RPART, gr2, br2, Hct, 256, 1);

  // ---- layer 3: 256 -> 256, identity residual (MFMA xa, N=256 gemm) ----
  k_xa_mfma<<<dim3(75, 8), 256, 0, stream>>>(Hct, ATb + 3*3072, XA, 256, 768);
  k_gemm2<<<MT, 512, 0, stream>>>(XA, W3t, Z, 768);
  k_bn_part_win<<<dim3(256, 8), 256, 0, stream>>>(Z, PART, 256);
  k_apply2<<<8*256, 256, 0, stream>>>(Z, nullptr, Hct, PART, g3, b3,
      nullptr, nullptr, nullptr, Hct, 256, 2);

  // ---- head ----
  k_pool<<<2400, 256, 0, stream>>>(Hct, HP);
  k_fout<<<dim3(10, 8), 256, 0, stream>>>(HP, foutW, foutb, out);
}